// Round 14
// baseline (244.332 us; speedup 1.0000x reference)
//
#include <hip/hip_runtime.h>
#include <hip/hip_bf16.h>
#include <math.h>

#define NUSER 60000
#define NITEM 60000
#define NNODE 120000
#define BSH 9
#define NB 235           // ceil(NNODE / 512) edge buckets
#define PBSH 7
#define PB 938           // ceil(NNODE / 128) pair buckets
#define CAP 8192         // per-bucket LDS capacity (edge sort)

typedef __attribute__((ext_vector_type(8))) short bf16x8;
typedef __attribute__((ext_vector_type(4))) float f32x4;
typedef __attribute__((ext_vector_type(2))) float f32x2;
typedef __attribute__((ext_vector_type(4))) unsigned short u16x4;

__device__ __forceinline__ float leaky02(float x) { return x > 0.f ? x : 0.2f * x; }

__device__ __forceinline__ float inv_ord(unsigned int u) {
  unsigned int bits = (u & 0x80000000u) ? (u & 0x7FFFFFFFu) : ~u;
  return __uint_as_float(bits);
}
__device__ __forceinline__ unsigned int ord_of(float f) {
  unsigned int u = __float_as_uint(f);
  return (u & 0x80000000u) ? ~u : (u | 0x80000000u);
}
__device__ __forceinline__ short f2bs(float f) {
  __hip_bfloat16 h = __float2bfloat16(f);
  return *reinterpret_cast<short*>(&h);
}

__device__ __forceinline__ void f8fma(f32x2& acc, float w, unsigned int u) {
  f32x2 zz = __builtin_amdgcn_cvt_pk_f32_fp8(u, false);
  f32x2 ww; ww.x = w; ww.y = w;
  acc = __builtin_elementwise_fma(ww, zz, acc);
}
__device__ __forceinline__ void fp8dot(f32x2& acc, unsigned int ua, unsigned int ub) {
  f32x2 a0 = __builtin_amdgcn_cvt_pk_f32_fp8(ua, false);
  f32x2 a1 = __builtin_amdgcn_cvt_pk_f32_fp8(ua, true);
  f32x2 b0 = __builtin_amdgcn_cvt_pk_f32_fp8(ub, false);
  f32x2 b1 = __builtin_amdgcn_cvt_pk_f32_fp8(ub, true);
  acc = __builtin_elementwise_fma(a0, b0, acc);
  acc = __builtin_elementwise_fma(a1, b1, acc);
}

// ---- K1: bcount (0..511) + prep (512..736) + pair-count (737..864)
__global__ __launch_bounds__(256) void prep_count_kernel(
    const float* __restrict__ Wu, const float* __restrict__ bu, const float* __restrict__ Wi,
    const float* __restrict__ bi, const float* __restrict__ Wg, const float* __restrict__ Wp,
    __hip_bfloat16* __restrict__ Bp_u, __hip_bfloat16* __restrict__ Bp_i,
    __hip_bfloat16* __restrict__ Bp_p, float* __restrict__ bf_u, float* __restrict__ bf_i,
    const int* __restrict__ dst, int* __restrict__ btotal, int E,
    const int* __restrict__ ps, const int* __restrict__ ns, int* __restrict__ pbtotal, int P) {
  __shared__ int cnt[PB];
  if (blockIdx.x < 512) {
    int bid = blockIdx.x;
    for (int t = threadIdx.x; t < NB; t += 256) cnt[t] = 0;
    __syncthreads();
    for (int i = bid * 256 + threadIdx.x; i < E; i += 512 * 256)
      atomicAdd(&cnt[dst[i] >> BSH], 1);
    __syncthreads();
    for (int t = threadIdx.x; t < NB; t += 256)
      if (cnt[t]) atomicAdd(&btotal[t], cnt[t]);
    return;
  }
  if (blockIdx.x >= 737) {
    int bid = blockIdx.x - 737;
    int TOT = 2 * P;
    for (int t = threadIdx.x; t < PB; t += 256) cnt[t] = 0;
    __syncthreads();
    for (int i = bid * 256 + threadIdx.x; i < TOT; i += 128 * 256) {
      int a = (i < P) ? ps[i] : ns[i - P];
      atomicAdd(&cnt[a >> PBSH], 1);
    }
    __syncthreads();
    for (int t = threadIdx.x; t < PB; t += 256)
      if (cnt[t]) atomicAdd(&pbtotal[t], cnt[t]);
    return;
  }
  int t = (blockIdx.x - 512) * 256 + threadIdx.x;
  if (t < 32768) {
    int j = t & 7, lane = (t >> 3) & 63, rest = t >> 9;
    int nt = rest & 7, ks = rest >> 3;
    int k = ks * 32 + ((lane >> 4) << 3) + j;
    int n = nt * 16 + (lane & 15);
    float acc = 0.f;
#pragma unroll 8
    for (int jj = 0; jj < 128; ++jj) acc = fmaf(Wu[k * 128 + jj], Wg[jj * 128 + n], acc);
    Bp_u[t] = __float2bfloat16(acc);
  } else if (t < 49152) {
    int tt = t - 32768;
    int j = tt & 7, lane = (tt >> 3) & 63, rest = tt >> 9;
    int nt = rest & 7, ks = rest >> 3;
    int k = ks * 32 + ((lane >> 4) << 3) + j;
    int n = nt * 16 + (lane & 15);
    float acc = 0.f;
#pragma unroll 8
    for (int jj = 0; jj < 128; ++jj) acc = fmaf(Wi[k * 128 + jj], Wg[jj * 128 + n], acc);
    Bp_i[tt] = __float2bfloat16(acc);
  } else if (t < 57344) {
    int tt = t - 49152;
    int j = tt & 7, lane = (tt >> 3) & 63, rest = tt >> 9;
    int nt = rest & 3, ks = rest >> 2;
    int k = ks * 32 + ((lane >> 4) << 3) + j;
    int n = nt * 16 + (lane & 15);
    Bp_p[tt] = __float2bfloat16(Wp[k * 64 + n]);
  } else if (t < 57344 + 256) {
    int n = t - 57344;
    if (n < 128) {
      float acc = 0.f;
      for (int jj = 0; jj < 128; ++jj) acc = fmaf(bu[jj], Wg[jj * 128 + n], acc);
      bf_u[n] = acc;
    } else {
      int nn = n - 128;
      float acc = 0.f;
      for (int jj = 0; jj < 128; ++jj) acc = fmaf(bi[jj], Wg[jj * 128 + nn], acc);
      bf_i[nn] = acc;
    }
  }
}

// ---- K2: scan edge buckets (NB) and pair buckets (PB), one block.
__global__ void bscan_kernel(const int* __restrict__ btotal, int* __restrict__ bstart,
                             int* __restrict__ gcur, const int* __restrict__ pbtotal,
                             int* __restrict__ pbstart, int* __restrict__ pgcur) {
  __shared__ int s[256];
  int t = threadIdx.x;
  int v = (t < NB) ? btotal[t] : 0;
  s[t] = v;
  __syncthreads();
  for (int off = 1; off < 256; off <<= 1) {
    int a = (t >= off) ? s[t - off] : 0;
    __syncthreads();
    s[t] += a;
    __syncthreads();
  }
  int excl = s[t] - v;
  if (t < NB) { bstart[t] = excl; gcur[t] = excl; }
  if (t == NB - 1) bstart[NB] = s[t];
  __syncthreads();
  int v4[4], sum4 = 0;
#pragma unroll
  for (int k = 0; k < 4; ++k) {
    int idx = t * 4 + k;
    v4[k] = (idx < PB) ? pbtotal[idx] : 0;
    sum4 += v4[k];
  }
  s[t] = sum4;
  __syncthreads();
  for (int off = 1; off < 256; off <<= 1) {
    int a = (t >= off) ? s[t - off] : 0;
    __syncthreads();
    s[t] += a;
    __syncthreads();
  }
  int run = s[t] - sum4;
#pragma unroll
  for (int k = 0; k < 4; ++k) {
    int idx = t * 4 + k;
    if (idx < PB) { pbstart[idx] = run; pgcur[idx] = run; }
    run += v4[k];
  }
  if (t == 255) pbstart[PB] = s[255];
}

// ---- K3a: edge scatter (0..SC-1) + pair scatter (SC..SC+PSC-1), standalone.
__global__ __launch_bounds__(256) void scatter_kernel(
    const int* __restrict__ src, const int* __restrict__ dst, int* __restrict__ gcur,
    unsigned int* __restrict__ scratch, int E, int SC,
    const int* __restrict__ ps, const int* __restrict__ pd, const int* __restrict__ ns,
    const int* __restrict__ nd, int* __restrict__ pgcur, uint2* __restrict__ pairbuf, int P) {
  __shared__ int smem2[2 * PB];
  int bx = blockIdx.x;
  if (bx < SC) {
    int* cnt = smem2;
    int* basep = smem2 + NB;
    for (int t = threadIdx.x; t < NB; t += 256) cnt[t] = 0;
    __syncthreads();
    const int i0 = bx * 4096;
    unsigned int v_[16];
    int b_[16], r_[16];
#pragma unroll
    for (int j = 0; j < 16; ++j) {
      int i = i0 + j * 256 + threadIdx.x;
      b_[j] = -1;
      if (i < E) {
        int d = dst[i];
        int s = src[i];
        int b = d >> BSH;
        b_[j] = b;
        r_[j] = atomicAdd(&cnt[b], 1);
        v_[j] = (unsigned int)s | ((unsigned int)(d & 511) << 17);
      }
    }
    __syncthreads();
    for (int t = threadIdx.x; t < NB; t += 256)
      basep[t] = cnt[t] ? atomicAdd(&gcur[t], cnt[t]) : 0;
    __syncthreads();
#pragma unroll
    for (int j = 0; j < 16; ++j)
      if (b_[j] >= 0) scratch[basep[b_[j]] + r_[j]] = v_[j];
    return;
  }
  // pair scatter
  int* cnt = smem2;
  int* basep = smem2 + PB;
  for (int t = threadIdx.x; t < PB; t += 256) cnt[t] = 0;
  __syncthreads();
  const int TOT = 2 * P;
  const int i0 = (bx - SC) * 4096;
  unsigned int x_[16], y_[16];
  int b_[16], r_[16];
#pragma unroll
  for (int j = 0; j < 16; ++j) {
    int i = i0 + j * 256 + threadIdx.x;
    b_[j] = -1;
    if (i < TOT) {
      int a, b, wh;
      if (i < P) { a = ps[i]; b = pd[i]; wh = 0; }
      else { a = ns[i - P]; b = nd[i - P]; wh = 1; }
      int bk = a >> PBSH;
      b_[j] = bk;
      r_[j] = atomicAdd(&cnt[bk], 1);
      x_[j] = (unsigned int)a | ((unsigned int)wh << 17);
      y_[j] = (unsigned int)b;
    }
  }
  __syncthreads();
  for (int t = threadIdx.x; t < PB; t += 256)
    basep[t] = cnt[t] ? atomicAdd(&pgcur[t], cnt[t]) : 0;
  __syncthreads();
#pragma unroll
  for (int j = 0; j < 16; ++j)
    if (b_[j] >= 0) pairbuf[basep[b_[j]] + r_[j]] = make_uint2(x_[j], y_[j]);
}

// ---- K3b: z GEMM. Chunked A-prefetch: 8 float4 (one 128-col chunk) in registers,
// prefetch chunk c+1 while computing chunk c (8-16 loads in flight per wave).
// Single A-fragment per wave (16 rows), 64 rows/block. 2-pass fp32 LDS epilogue.
template <int K>
__device__ __forceinline__ void zgemm_body(
    char* smem, const float* __restrict__ A, const __hip_bfloat16* __restrict__ Bp,
    const float* __restrict__ bias, const float* __restrict__ al, const float* __restrict__ ar,
    unsigned char* __restrict__ z8, float* __restrict__ el, float* __restrict__ er, int M,
    int blk) {
  const int lane = threadIdx.x & 63, wv = threadIdx.x >> 6;
  const int t = threadIdx.x;
  int arow = blk * 64 + wv * 16 + (lane & 15);
  if (arow >= M) arow = M - 1;
  const float* a0p = A + (size_t)arow * K + ((lane >> 4) << 3);
  const bf16x8* bp = (const bf16x8*)Bp;
  f32x4 acc[8] = {};
  constexpr int NCH = K / 128;
  float4 ab[8];
#pragma unroll
  for (int q = 0; q < 8; ++q)
    ab[q] = *(const float4*)(a0p + (q >> 1) * 32 + (q & 1) * 4);
#pragma unroll
  for (int c = 0; c < NCH; ++c) {
    float4 an[8];
    if (c + 1 < NCH) {
#pragma unroll
      for (int q = 0; q < 8; ++q)
        an[q] = *(const float4*)(a0p + (c + 1) * 128 + (q >> 1) * 32 + (q & 1) * 4);
    }
#pragma unroll
    for (int s = 0; s < 4; ++s) {
      int ks = c * 4 + s;
      float4 a1 = ab[s * 2], a2 = ab[s * 2 + 1];
      bf16x8 af;
      af[0] = f2bs(a1.x); af[1] = f2bs(a1.y); af[2] = f2bs(a1.z); af[3] = f2bs(a1.w);
      af[4] = f2bs(a2.x); af[5] = f2bs(a2.y); af[6] = f2bs(a2.z); af[7] = f2bs(a2.w);
#pragma unroll
      for (int nt = 0; nt < 8; ++nt) {
        bf16x8 bfr = bp[(ks * 8 + nt) * 64 + lane];
        acc[nt] = __builtin_amdgcn_mfma_f32_16x16x32_bf16(af, bfr, acc[nt], 0, 0, 0);
      }
    }
    if (c + 1 < NCH) {
#pragma unroll
      for (int q = 0; q < 8; ++q) ab[q] = an[q];
    }
  }
  // epilogue: two 64-col passes through 64x68 fp32 LDS; fused el/er + fp8 z
  float(*lds2)[68] = (float(*)[68])smem;
  int row = t >> 2, qq = t & 3;
  int gm = blk * 64 + row;
  float pl = 0.f, pr = 0.f;
#pragma unroll
  for (int p = 0; p < 2; ++p) {
    __syncthreads();
#pragma unroll
    for (int nt = p * 4; nt < p * 4 + 4; ++nt) {
      float b = bias[nt * 16 + (lane & 15)];
#pragma unroll
      for (int r = 0; r < 4; ++r)
        lds2[wv * 16 + (lane >> 4) * 4 + r][(nt & 3) * 16 + (lane & 15)] = acc[nt][r] + b;
    }
    __syncthreads();
    if (gm < M) {
#pragma unroll
      for (int v4 = 0; v4 < 2; ++v4) {
        float f[8];
#pragma unroll
        for (int j = 0; j < 8; ++j) {
          f[j] = lds2[row][qq * 16 + v4 * 8 + j];
          int c = p * 64 + qq * 16 + v4 * 8 + j;
          pl = fmaf(f[j], al[c], pl);
          pr = fmaf(f[j], ar[c], pr);
        }
        unsigned int w0 = (unsigned int)__builtin_amdgcn_cvt_pk_fp8_f32(f[0], f[1], 0, false);
        w0 = (unsigned int)__builtin_amdgcn_cvt_pk_fp8_f32(f[2], f[3], (int)w0, true);
        unsigned int w1 = (unsigned int)__builtin_amdgcn_cvt_pk_fp8_f32(f[4], f[5], 0, false);
        w1 = (unsigned int)__builtin_amdgcn_cvt_pk_fp8_f32(f[6], f[7], (int)w1, true);
        uint2 st; st.x = w0; st.y = w1;
        *(uint2*)(z8 + (size_t)gm * 128 + p * 64 + qq * 16 + v4 * 8) = st;
      }
    }
  }
  pl += __shfl_xor(pl, 1, 64); pl += __shfl_xor(pl, 2, 64);
  pr += __shfl_xor(pr, 1, 64); pr += __shfl_xor(pr, 2, 64);
  if (qq == 0 && gm < M) { el[gm] = pl; er[gm] = pr; }
}

__global__ __launch_bounds__(256) void zgemm_kernel(
    const float* __restrict__ Au, const __hip_bfloat16* __restrict__ Bpu,
    const float* __restrict__ bfu, const float* __restrict__ Ai,
    const __hip_bfloat16* __restrict__ Bpi, const float* __restrict__ bfi,
    const float* __restrict__ al, const float* __restrict__ ar, unsigned char* __restrict__ z8,
    float* __restrict__ el, float* __restrict__ er, int GU) {
  __shared__ __align__(16) char smem[17408];
  int gb = blockIdx.x;
  if (gb < GU)
    zgemm_body<256>(smem, Au, Bpu, bfu, al, ar, z8, el, er, NUSER, gb);
  else
    zgemm_body<128>(smem, Ai, Bpi, bfi, al, ar, z8 + (size_t)NUSER * 128, el + NUSER, er + NUSER,
                    NITEM, gb - GU);
}

// ---- K4: per-bucket LDS counting sort -> ssrc (dst-sorted) + offs
__global__ __launch_bounds__(512) void bsort_kernel(const unsigned int* __restrict__ scratch,
                                                    const int* __restrict__ bstart,
                                                    int* __restrict__ offs, int* __restrict__ ssrc) {
  __shared__ unsigned int buf[CAP];
  __shared__ int cnt[512], scn[512], cur[512];
  int b = blockIdx.x, t = threadIdx.x;
  int s = bstart[b], e = bstart[b + 1], n = e - s;
  int d0 = b << BSH;
  int ndst = NNODE - d0;
  if (ndst > 512) ndst = 512;
  cnt[t] = 0;
  cur[t] = 0;
  __syncthreads();
  bool fit = (n <= CAP);
  if (fit) {
    for (int i = t; i < n; i += 512) {
      unsigned int v = scratch[s + i];
      buf[i] = v;
      atomicAdd(&cnt[v >> 17], 1);
    }
  } else {
    for (int i = t; i < n; i += 512) atomicAdd(&cnt[scratch[s + i] >> 17], 1);
  }
  __syncthreads();
  scn[t] = cnt[t];
  __syncthreads();
  for (int off = 1; off < 512; off <<= 1) {
    int a = (t >= off) ? scn[t - off] : 0;
    __syncthreads();
    scn[t] += a;
    __syncthreads();
  }
  int start = scn[t] - cnt[t];
  if (t < ndst) offs[d0 + t] = s + start;
  if (b == NB - 1 && t == 0) offs[NNODE] = e;
  __syncthreads();
  cnt[t] = start;
  __syncthreads();
  if (fit) {
    for (int i = t; i < n; i += 512) {
      unsigned int v = buf[i];
      int dl = v >> 17;
      int r = atomicAdd(&cur[dl], 1);
      ssrc[s + cnt[dl] + r] = (int)(v & 0x1FFFFu);
    }
  } else {
    for (int i = t; i < n; i += 512) {
      unsigned int v = scratch[s + i];
      int dl = v >> 17;
      int r = atomicAdd(&cur[dl], 1);
      ssrc[s + cnt[dl] + r] = (int)(v & 0x1FFFFu);
    }
  }
}

// ---- K5: GAT aggregation (unchanged)
__global__ __launch_bounds__(256) void aggregate_kernel(
    const unsigned char* __restrict__ z8, const float* __restrict__ el,
    const float* __restrict__ er, const int* __restrict__ offs, const int* __restrict__ ssrc,
    const float* __restrict__ gat_bias, __hip_bfloat16* __restrict__ h,
    unsigned char* __restrict__ h8) {
  __shared__ __align__(16) float2 ew[4][128];
  int wv = threadIdx.x >> 6, lane = threadIdx.x & 63;
  int d = blockIdx.x * 4 + wv;
  int s0 = offs[d], s1 = offs[d + 1];
  int deg = s1 - s0;
  float erd = er[d];
  const unsigned short* zw = (const unsigned short*)z8;
  f32x2 acc = {0.f, 0.f};
  float ssum = 0.f;
  if (deg <= 128) {
    float w0 = 0.f, w1 = 0.f;
    int o0 = 0, o1 = 0;
    if (lane < deg) { int s = ssrc[s0 + lane]; o0 = s << 6; w0 = __expf(leaky02(el[s] + erd)); }
    if (64 + lane < deg) { int s = ssrc[s0 + 64 + lane]; o1 = s << 6; w1 = __expf(leaky02(el[s] + erd)); }
    ew[wv][lane] = make_float2(w0, __int_as_float(o0));
    ew[wv][64 + lane] = make_float2(w1, __int_as_float(o1));
    __builtin_amdgcn_wave_barrier();
    int i = 0;
    for (; i + 8 <= deg; i += 8) {
      float4 p0 = *(const float4*)&ew[wv][i];
      float4 p1 = *(const float4*)&ew[wv][i + 2];
      float4 p2 = *(const float4*)&ew[wv][i + 4];
      float4 p3 = *(const float4*)&ew[wv][i + 6];
      unsigned int u0 = zw[__float_as_uint(p0.y) + lane];
      unsigned int u1 = zw[__float_as_uint(p0.w) + lane];
      unsigned int u2 = zw[__float_as_uint(p1.y) + lane];
      unsigned int u3 = zw[__float_as_uint(p1.w) + lane];
      unsigned int u4 = zw[__float_as_uint(p2.y) + lane];
      unsigned int u5 = zw[__float_as_uint(p2.w) + lane];
      unsigned int u6 = zw[__float_as_uint(p3.y) + lane];
      unsigned int u7 = zw[__float_as_uint(p3.w) + lane];
      ssum += ((p0.x + p0.z) + (p1.x + p1.z)) + ((p2.x + p2.z) + (p3.x + p3.z));
      f8fma(acc, p0.x, u0); f8fma(acc, p0.z, u1);
      f8fma(acc, p1.x, u2); f8fma(acc, p1.z, u3);
      f8fma(acc, p2.x, u4); f8fma(acc, p2.z, u5);
      f8fma(acc, p3.x, u6); f8fma(acc, p3.z, u7);
    }
    for (; i + 2 <= deg; i += 2) {
      float4 p = *(const float4*)&ew[wv][i];
      unsigned int ua = zw[__float_as_uint(p.y) + lane];
      unsigned int ub = zw[__float_as_uint(p.w) + lane];
      ssum += p.x + p.z;
      f8fma(acc, p.x, ua); f8fma(acc, p.z, ub);
    }
    if (i < deg) {
      float2 pp = ew[wv][i];
      unsigned int u = zw[__float_as_uint(pp.y) + lane];
      ssum += pp.x;
      f8fma(acc, pp.x, u);
    }
  } else {
    for (int i2 = s0; i2 < s1; ++i2) {
      int s = ssrc[i2];
      float w = __expf(leaky02(el[s] + erd));
      ssum += w;
      unsigned int u = zw[((unsigned int)s << 6) + lane];
      f8fma(acc, w, u);
    }
  }
  float inv = 1.f / ssum;
  float o0f = acc.x * inv + gat_bias[lane * 2];
  float o1f = acc.y * inv + gat_bias[lane * 2 + 1];
  o0f = (o0f > 0.f) ? o0f : (__expf(o0f) - 1.f);
  o1f = (o1f > 0.f) ? o1f : (__expf(o1f) - 1.f);
  ushort2 ov;
  ov.x = (unsigned short)((unsigned int)f2bs(o0f) & 0xFFFFu);
  ov.y = (unsigned short)((unsigned int)f2bs(o1f) & 0xFFFFu);
  *(ushort2*)((unsigned short*)h + (size_t)d * 128 + lane * 2) = ov;
  int pk8 = __builtin_amdgcn_cvt_pk_fp8_f32(o0f, o1f, 0, false);
  *(unsigned short*)(h8 + (size_t)d * 128 + lane * 2) = (unsigned short)(pk8 & 0xFFFF);
}

// ---- K6: predgemm (blocks 0..GP-1) + bucketed link scores (blocks GP..GP+PB-1).
__global__ __launch_bounds__(256) void scorepred_kernel(
    const unsigned char* __restrict__ h8, const uint2* __restrict__ pairbuf,
    const int* __restrict__ pbstart, float* __restrict__ l_all,
    unsigned int* __restrict__ maxacc,
    const __hip_bfloat16* __restrict__ h, const __hip_bfloat16* __restrict__ Bp,
    const float* __restrict__ bias, float* __restrict__ outp, int GP) {
  if ((int)blockIdx.x < GP) {
    const int lane = threadIdx.x & 63, wv = threadIdx.x >> 6;
    const int m0 = blockIdx.x * 64 + wv * 16;
    int arow = m0 + (lane & 15);
    if (arow >= NUSER) arow = NUSER - 1;
    const bf16x8* a0 = (const bf16x8*)(h + (size_t)arow * 128) + (lane >> 4);
    const bf16x8* bp = (const bf16x8*)Bp;
    f32x4 acc[4] = {};
#pragma unroll
    for (int ks = 0; ks < 4; ++ks) {
      bf16x8 af = a0[ks * 4];
#pragma unroll
      for (int nt = 0; nt < 4; ++nt) {
        bf16x8 bfr = bp[(ks * 4 + nt) * 64 + lane];
        acc[nt] = __builtin_amdgcn_mfma_f32_16x16x32_bf16(af, bfr, acc[nt], 0, 0, 0);
      }
    }
#pragma unroll
    for (int nt = 0; nt < 4; ++nt) {
      int col = nt * 16 + (lane & 15);
      float b = bias[col];
#pragma unroll
      for (int r = 0; r < 4; ++r) {
        int m = m0 + (lane >> 4) * 4 + r;
        if (m < NUSER) outp[(size_t)m * 64 + col] = acc[nt][r] + b;
      }
    }
    return;
  }
  const int sb = blockIdx.x - GP;
  const int g8 = threadIdx.x >> 3, l8 = threadIdx.x & 7;
  const uint4* h4 = (const uint4*)h8;
  const int sP = pbstart[sb], eP = pbstart[sb + 1];
  float mpos = -1e30f, mneg = -1e30f;

  int i = sP + g8;
  uint2 prC = make_uint2(0, 0);
  uint4 vaC = {0, 0, 0, 0}, vbC = {0, 0, 0, 0};
  if (i < eP) {
    prC = pairbuf[i];
    vaC = h4[(size_t)(prC.x & 0x1FFFFu) * 8 + l8];
    vbC = h4[(size_t)prC.y * 8 + l8];
  }
  int i1 = i + 32;
  uint2 prN = make_uint2(0, 0);
  if (i1 < eP) prN = pairbuf[i1];

  while (i < eP) {
    uint4 vaN = {0, 0, 0, 0}, vbN = {0, 0, 0, 0};
    if (i1 < eP) {
      vaN = h4[(size_t)(prN.x & 0x1FFFFu) * 8 + l8];
      vbN = h4[(size_t)prN.y * 8 + l8];
    }
    int i2 = i1 + 32;
    uint2 prN2 = make_uint2(0, 0);
    if (i2 < eP) prN2 = pairbuf[i2];
    f32x2 acc = {0.f, 0.f};
    fp8dot(acc, vaC.x, vbC.x);
    fp8dot(acc, vaC.y, vbC.y);
    fp8dot(acc, vaC.z, vbC.z);
    fp8dot(acc, vaC.w, vbC.w);
    float s = acc.x + acc.y;
    s += __shfl_xor(s, 1, 8);
    s += __shfl_xor(s, 2, 8);
    s += __shfl_xor(s, 4, 8);
    float lv = fminf(s, 0.f) - log1pf(__expf(-fabsf(s)));
    bool neg = (prC.x >> 17) & 1u;
    if (l8 == 0) l_all[i] = lv;
    if (neg) mneg = fmaxf(mneg, lv); else mpos = fmaxf(mpos, lv);
    i = i1; i1 = i2;
    prC = prN; prN = prN2;
    vaC = vaN; vbC = vbN;
  }
  __shared__ float red0[256], red1[256];
  red0[threadIdx.x] = mpos;
  red1[threadIdx.x] = mneg;
  __syncthreads();
  for (int off = 128; off; off >>= 1) {
    if (threadIdx.x < off) {
      red0[threadIdx.x] = fmaxf(red0[threadIdx.x], red0[threadIdx.x + off]);
      red1[threadIdx.x] = fmaxf(red1[threadIdx.x], red1[threadIdx.x + off]);
    }
    __syncthreads();
  }
  if (threadIdx.x == 0) {
    if (red0[0] > -1e29f) atomicMax(maxacc + 0, ord_of(red0[0]));
    if (red1[0] > -1e29f) atomicMax(maxacc + 1, ord_of(red1[0]));
  }
}

// ---- K7: thresholded sum over bucket-ordered l_all; last block writes loss.
__global__ __launch_bounds__(256) void loss_sum_kernel(const float* __restrict__ l_all,
                                                       const uint2* __restrict__ pairbuf,
                                                       const unsigned int* __restrict__ maxacc,
                                                       const int* __restrict__ alpha,
                                                       float* __restrict__ sums,
                                                       unsigned int* __restrict__ fincnt,
                                                       float* __restrict__ out, int TOT) {
  __shared__ float sd0[256], sd1[256];
  float a = (float)alpha[0];
  float kT = (0.5f <= a) ? 0.5f : a;
  float hold0 = kT * inv_ord(maxacc[0]);
  float hold1 = kT * inv_ord(maxacc[1]);
  float s0 = 0.f, s1 = 0.f;
  for (int i = blockIdx.x * 256 + threadIdx.x; i < TOT; i += gridDim.x * 256) {
    float v = l_all[i];
    if ((pairbuf[i].x >> 17) & 1u) {
      if (!(v > hold1)) s1 += v;
    } else {
      if (!(v > hold0)) s0 += v;
    }
  }
  sd0[threadIdx.x] = s0;
  sd1[threadIdx.x] = s1;
  __syncthreads();
  for (int off = 128; off; off >>= 1) {
    if (threadIdx.x < off) {
      sd0[threadIdx.x] += sd0[threadIdx.x + off];
      sd1[threadIdx.x] += sd1[threadIdx.x + off];
    }
    __syncthreads();
  }
  if (threadIdx.x == 0) {
    atomicAdd(&sums[0], sd0[0]);
    atomicAdd(&sums[1], sd1[0]);
    __threadfence();
    unsigned int t = atomicAdd(fincnt, 1u);
    if (t == gridDim.x - 1) {
      float f0 = atomicAdd(&sums[0], 0.f);
      float f1 = atomicAdd(&sums[1], 0.f);
      out[0] = -(f0 + f1);
    }
  }
}

extern "C" void kernel_launch(void* const* d_in, const int* in_sizes, int n_in,
                              void* d_out, int out_size, void* d_ws, size_t ws_size,
                              hipStream_t stream) {
  const float* feat_user = (const float*)d_in[0];
  const float* feat_item = (const float*)d_in[1];
  const float* W_user = (const float*)d_in[2];
  const float* b_user = (const float*)d_in[3];
  const float* W_item = (const float*)d_in[4];
  const float* b_item = (const float*)d_in[5];
  const float* W_gat = (const float*)d_in[6];
  const float* attn_l = (const float*)d_in[7];
  const float* attn_r = (const float*)d_in[8];
  const float* gat_bias = (const float*)d_in[9];
  const float* W_pred = (const float*)d_in[10];
  const float* b_pred = (const float*)d_in[11];
  const int* src = (const int*)d_in[12];
  const int* dst = (const int*)d_in[13];
  const int* pos_src = (const int*)d_in[14];
  const int* pos_dst = (const int*)d_in[15];
  const int* neg_src = (const int*)d_in[16];
  const int* neg_dst = (const int*)d_in[17];
  const int* alpha = (const int*)d_in[18];
  const int E = in_sizes[12];
  const int P = in_sizes[14];
  const int TOT = 2 * P;

  char* p = (char*)d_ws;
  auto alloc = [&](size_t bytes) {
    char* r = p;
    p += (bytes + 255) & ~(size_t)255;
    return r;
  };
  unsigned char* z8 = (unsigned char*)alloc((size_t)NNODE * 128);
  __hip_bfloat16* h = (__hip_bfloat16*)alloc((size_t)NNODE * 128 * 2);
  unsigned char* h8 = (unsigned char*)alloc((size_t)NNODE * 128);
  float* el = (float*)alloc((size_t)NNODE * 4);
  float* er = (float*)alloc((size_t)NNODE * 4);
  __hip_bfloat16* Bp_u = (__hip_bfloat16*)alloc(256 * 128 * 2);
  __hip_bfloat16* Bp_i = (__hip_bfloat16*)alloc(128 * 128 * 2);
  __hip_bfloat16* Bp_p = (__hip_bfloat16*)alloc(128 * 64 * 2);
  float* bf_u = (float*)alloc(128 * 4);
  float* bf_i = (float*)alloc(128 * 4);
  int* offs = (int*)alloc((size_t)(NNODE + 4) * 4);
  int* ssrc = (int*)alloc((size_t)E * 4);
  unsigned int* scratch = (unsigned int*)alloc((size_t)E * 4);
  uint2* pairbuf = (uint2*)alloc((size_t)TOT * 8);
  float* l_all = (float*)alloc((size_t)TOT * 4);
  int* bstart = (int*)alloc((NB + 1) * 4);
  int* gcur = (int*)alloc(NB * 4);
  int* pbstart = (int*)alloc((PB + 1) * 4);
  int* pgcur = (int*)alloc(PB * 4);
  // zero region: btotal[NB] | pbtotal[PB] | maxacc[2] | sums[2] | fincnt[1]
  int* btotal = (int*)alloc((NB + PB + 8) * 4);
  int* pbtotal = btotal + NB;
  unsigned int* maxacc = (unsigned int*)(pbtotal + PB);
  float* sums = (float*)(maxacc + 2);
  unsigned int* fincnt = (unsigned int*)(sums + 2);

  hipMemsetAsync(btotal, 0, (NB + PB + 8) * 4, stream);

  // K1: bucket counts + weight prep + pair counts (independent, fused)
  prep_count_kernel<<<512 + 225 + 128, 256, 0, stream>>>(
      W_user, b_user, W_item, b_item, W_gat, W_pred, Bp_u, Bp_i, Bp_p, bf_u, bf_i, dst, btotal, E,
      pos_src, neg_src, pbtotal, P);
  // K2: scan both bucket sets
  bscan_kernel<<<1, 256, 0, stream>>>(btotal, bstart, gcur, pbtotal, pbstart, pgcur);
  // K3a: edge + pair scatter (standalone for clean profiling)
  const int SC = (E + 4095) / 4096;
  const int PSC = (TOT + 4095) / 4096;
  scatter_kernel<<<SC + PSC, 256, 0, stream>>>(src, dst, gcur, scratch, E, SC, pos_src, pos_dst,
                                               neg_src, neg_dst, pgcur, pairbuf, P);
  // K3b: z GEMM with chunked A-prefetch
  const int GU = (NUSER + 63) / 64, GI = (NITEM + 63) / 64;
  zgemm_kernel<<<GU + GI, 256, 0, stream>>>(feat_user, Bp_u, bf_u, feat_item, Bp_i, bf_i, attn_l,
                                            attn_r, z8, el, er, GU);
  // K4: per-bucket counting sort -> CSR
  bsort_kernel<<<NB, 512, 0, stream>>>(scratch, bstart, offs, ssrc);
  // K5: GAT edge-softmax aggregation -> h (bf16) + h8 (fp8)
  aggregate_kernel<<<NNODE / 4, 256, 0, stream>>>(z8, el, er, offs, ssrc, gat_bias, h, h8);
  // K6: predgemm + bucketed link scores
  const int GP = (NUSER + 63) / 64;
  scorepred_kernel<<<GP + PB, 256, 0, stream>>>(h8, pairbuf, pbstart, l_all, maxacc, h, Bp_p,
                                                b_pred, (float*)d_out + 1, GP);
  // K7: thresholded loss sums + final loss write (last block)
  loss_sum_kernel<<<1024, 256, 0, stream>>>(l_all, pairbuf, maxacc, alpha, sums, fincnt,
                                            (float*)d_out, TOT);

  (void)n_in; (void)out_size; (void)ws_size;
}

// Round 15
// 236.133 us; speedup vs baseline: 1.0347x; 1.0347x over previous
//
#include <hip/hip_runtime.h>
#include <hip/hip_bf16.h>
#include <math.h>

#define NUSER 60000
#define NITEM 60000
#define NNODE 120000
#define BSH 9
#define NB 235           // ceil(NNODE / 512) edge buckets
#define PBSH 7
#define PB 938           // ceil(NNODE / 128) pair buckets
#define CAP 8192         // per-bucket LDS capacity (edge sort)

typedef __attribute__((ext_vector_type(8))) short bf16x8;
typedef __attribute__((ext_vector_type(4))) float f32x4;
typedef __attribute__((ext_vector_type(2))) float f32x2;
typedef __attribute__((ext_vector_type(4))) unsigned short u16x4;

__device__ __forceinline__ float leaky02(float x) { return x > 0.f ? x : 0.2f * x; }

__device__ __forceinline__ float inv_ord(unsigned int u) {
  unsigned int bits = (u & 0x80000000u) ? (u & 0x7FFFFFFFu) : ~u;
  return __uint_as_float(bits);
}
__device__ __forceinline__ unsigned int ord_of(float f) {
  unsigned int u = __float_as_uint(f);
  return (u & 0x80000000u) ? ~u : (u | 0x80000000u);
}
__device__ __forceinline__ short f2bs(float f) {
  __hip_bfloat16 h = __float2bfloat16(f);
  return *reinterpret_cast<short*>(&h);
}

// acc01/acc23 += w * unpack4(u)  (4 fp8 -> cols 4li..4li+3)
__device__ __forceinline__ void pairfma(f32x2& a01, f32x2& a23, float w, unsigned int u) {
  f32x2 lo = __builtin_amdgcn_cvt_pk_f32_fp8(u, false);
  f32x2 hi = __builtin_amdgcn_cvt_pk_f32_fp8(u, true);
  f32x2 ww; ww.x = w; ww.y = w;
  a01 = __builtin_elementwise_fma(ww, lo, a01);
  a23 = __builtin_elementwise_fma(ww, hi, a23);
}
__device__ __forceinline__ void fp8dot(f32x2& acc, unsigned int ua, unsigned int ub) {
  f32x2 a0 = __builtin_amdgcn_cvt_pk_f32_fp8(ua, false);
  f32x2 a1 = __builtin_amdgcn_cvt_pk_f32_fp8(ua, true);
  f32x2 b0 = __builtin_amdgcn_cvt_pk_f32_fp8(ub, false);
  f32x2 b1 = __builtin_amdgcn_cvt_pk_f32_fp8(ub, true);
  acc = __builtin_elementwise_fma(a0, b0, acc);
  acc = __builtin_elementwise_fma(a1, b1, acc);
}

// ---- K1: bcount (0..511) + prep (512..736) + pair-count (737..864)
__global__ __launch_bounds__(256) void prep_count_kernel(
    const float* __restrict__ Wu, const float* __restrict__ bu, const float* __restrict__ Wi,
    const float* __restrict__ bi, const float* __restrict__ Wg, const float* __restrict__ Wp,
    __hip_bfloat16* __restrict__ Bp_u, __hip_bfloat16* __restrict__ Bp_i,
    __hip_bfloat16* __restrict__ Bp_p, float* __restrict__ bf_u, float* __restrict__ bf_i,
    const int* __restrict__ dst, int* __restrict__ btotal, int E,
    const int* __restrict__ ps, const int* __restrict__ ns, int* __restrict__ pbtotal, int P) {
  __shared__ int cnt[PB];
  if (blockIdx.x < 512) {
    int bid = blockIdx.x;
    for (int t = threadIdx.x; t < NB; t += 256) cnt[t] = 0;
    __syncthreads();
    for (int i = bid * 256 + threadIdx.x; i < E; i += 512 * 256)
      atomicAdd(&cnt[dst[i] >> BSH], 1);
    __syncthreads();
    for (int t = threadIdx.x; t < NB; t += 256)
      if (cnt[t]) atomicAdd(&btotal[t], cnt[t]);
    return;
  }
  if (blockIdx.x >= 737) {
    int bid = blockIdx.x - 737;
    int TOT = 2 * P;
    for (int t = threadIdx.x; t < PB; t += 256) cnt[t] = 0;
    __syncthreads();
    for (int i = bid * 256 + threadIdx.x; i < TOT; i += 128 * 256) {
      int a = (i < P) ? ps[i] : ns[i - P];
      atomicAdd(&cnt[a >> PBSH], 1);
    }
    __syncthreads();
    for (int t = threadIdx.x; t < PB; t += 256)
      if (cnt[t]) atomicAdd(&pbtotal[t], cnt[t]);
    return;
  }
  int t = (blockIdx.x - 512) * 256 + threadIdx.x;
  if (t < 32768) {
    int j = t & 7, lane = (t >> 3) & 63, rest = t >> 9;
    int nt = rest & 7, ks = rest >> 3;
    int k = ks * 32 + ((lane >> 4) << 3) + j;
    int n = nt * 16 + (lane & 15);
    float acc = 0.f;
#pragma unroll 8
    for (int jj = 0; jj < 128; ++jj) acc = fmaf(Wu[k * 128 + jj], Wg[jj * 128 + n], acc);
    Bp_u[t] = __float2bfloat16(acc);
  } else if (t < 49152) {
    int tt = t - 32768;
    int j = tt & 7, lane = (tt >> 3) & 63, rest = tt >> 9;
    int nt = rest & 7, ks = rest >> 3;
    int k = ks * 32 + ((lane >> 4) << 3) + j;
    int n = nt * 16 + (lane & 15);
    float acc = 0.f;
#pragma unroll 8
    for (int jj = 0; jj < 128; ++jj) acc = fmaf(Wi[k * 128 + jj], Wg[jj * 128 + n], acc);
    Bp_i[tt] = __float2bfloat16(acc);
  } else if (t < 57344) {
    int tt = t - 49152;
    int j = tt & 7, lane = (tt >> 3) & 63, rest = tt >> 9;
    int nt = rest & 3, ks = rest >> 2;
    int k = ks * 32 + ((lane >> 4) << 3) + j;
    int n = nt * 16 + (lane & 15);
    Bp_p[tt] = __float2bfloat16(Wp[k * 64 + n]);
  } else if (t < 57344 + 256) {
    int n = t - 57344;
    if (n < 128) {
      float acc = 0.f;
      for (int jj = 0; jj < 128; ++jj) acc = fmaf(bu[jj], Wg[jj * 128 + n], acc);
      bf_u[n] = acc;
    } else {
      int nn = n - 128;
      float acc = 0.f;
      for (int jj = 0; jj < 128; ++jj) acc = fmaf(bi[jj], Wg[jj * 128 + nn], acc);
      bf_i[nn] = acc;
    }
  }
}

// ---- K2: scan edge buckets (NB) and pair buckets (PB), one block.
__global__ void bscan_kernel(const int* __restrict__ btotal, int* __restrict__ bstart,
                             int* __restrict__ gcur, const int* __restrict__ pbtotal,
                             int* __restrict__ pbstart, int* __restrict__ pgcur) {
  __shared__ int s[256];
  int t = threadIdx.x;
  int v = (t < NB) ? btotal[t] : 0;
  s[t] = v;
  __syncthreads();
  for (int off = 1; off < 256; off <<= 1) {
    int a = (t >= off) ? s[t - off] : 0;
    __syncthreads();
    s[t] += a;
    __syncthreads();
  }
  int excl = s[t] - v;
  if (t < NB) { bstart[t] = excl; gcur[t] = excl; }
  if (t == NB - 1) bstart[NB] = s[t];
  __syncthreads();
  int v4[4], sum4 = 0;
#pragma unroll
  for (int k = 0; k < 4; ++k) {
    int idx = t * 4 + k;
    v4[k] = (idx < PB) ? pbtotal[idx] : 0;
    sum4 += v4[k];
  }
  s[t] = sum4;
  __syncthreads();
  for (int off = 1; off < 256; off <<= 1) {
    int a = (t >= off) ? s[t - off] : 0;
    __syncthreads();
    s[t] += a;
    __syncthreads();
  }
  int run = s[t] - sum4;
#pragma unroll
  for (int k = 0; k < 4; ++k) {
    int idx = t * 4 + k;
    if (idx < PB) { pbstart[idx] = run; pgcur[idx] = run; }
    run += v4[k];
  }
  if (t == 255) pbstart[PB] = s[255];
}

// ---- z GEMM body: direct global A-fragment loads, MFMA, 2-pass fp32 LDS epilogue.
template <int K>
__device__ __forceinline__ void zgemm_body(
    char* smem, const float* __restrict__ A, const __hip_bfloat16* __restrict__ Bp,
    const float* __restrict__ bias, const float* __restrict__ al, const float* __restrict__ ar,
    unsigned char* __restrict__ z8, float* __restrict__ el, float* __restrict__ er, int M,
    int blk) {
  const int lane = threadIdx.x & 63, wv = threadIdx.x >> 6;
  const int t = threadIdx.x;
  int arow = blk * 64 + wv * 16 + (lane & 15);
  if (arow >= M) arow = M - 1;
  const float* a0 = A + (size_t)arow * K + ((lane >> 4) << 3);
  const bf16x8* bp = (const bf16x8*)Bp;
  f32x4 acc[8] = {};
#pragma unroll
  for (int ks = 0; ks < K / 32; ++ks) {
    float4 a1 = *(const float4*)(a0 + ks * 32);
    float4 a2 = *(const float4*)(a0 + ks * 32 + 4);
    bf16x8 af;
    af[0] = f2bs(a1.x); af[1] = f2bs(a1.y); af[2] = f2bs(a1.z); af[3] = f2bs(a1.w);
    af[4] = f2bs(a2.x); af[5] = f2bs(a2.y); af[6] = f2bs(a2.z); af[7] = f2bs(a2.w);
#pragma unroll
    for (int nt = 0; nt < 8; ++nt) {
      bf16x8 bfr = bp[(ks * 8 + nt) * 64 + lane];
      acc[nt] = __builtin_amdgcn_mfma_f32_16x16x32_bf16(af, bfr, acc[nt], 0, 0, 0);
    }
  }
  float(*lds2)[68] = (float(*)[68])smem;
  int row = t >> 2, qq = t & 3;
  int gm = blk * 64 + row;
  float pl = 0.f, pr = 0.f;
#pragma unroll
  for (int p = 0; p < 2; ++p) {
    __syncthreads();
#pragma unroll
    for (int nt = p * 4; nt < p * 4 + 4; ++nt) {
      float b = bias[nt * 16 + (lane & 15)];
#pragma unroll
      for (int r = 0; r < 4; ++r)
        lds2[wv * 16 + (lane >> 4) * 4 + r][(nt & 3) * 16 + (lane & 15)] = acc[nt][r] + b;
    }
    __syncthreads();
    if (gm < M) {
#pragma unroll
      for (int v4 = 0; v4 < 2; ++v4) {
        float f[8];
#pragma unroll
        for (int j = 0; j < 8; ++j) {
          f[j] = lds2[row][qq * 16 + v4 * 8 + j];
          int c = p * 64 + qq * 16 + v4 * 8 + j;
          pl = fmaf(f[j], al[c], pl);
          pr = fmaf(f[j], ar[c], pr);
        }
        unsigned int w0 = (unsigned int)__builtin_amdgcn_cvt_pk_fp8_f32(f[0], f[1], 0, false);
        w0 = (unsigned int)__builtin_amdgcn_cvt_pk_fp8_f32(f[2], f[3], (int)w0, true);
        unsigned int w1 = (unsigned int)__builtin_amdgcn_cvt_pk_fp8_f32(f[4], f[5], 0, false);
        w1 = (unsigned int)__builtin_amdgcn_cvt_pk_fp8_f32(f[6], f[7], (int)w1, true);
        uint2 st; st.x = w0; st.y = w1;
        *(uint2*)(z8 + (size_t)gm * 128 + p * 64 + qq * 16 + v4 * 8) = st;
      }
    }
  }
  pl += __shfl_xor(pl, 1, 64); pl += __shfl_xor(pl, 2, 64);
  pr += __shfl_xor(pr, 1, 64); pr += __shfl_xor(pr, 2, 64);
  if (qq == 0 && gm < M) { el[gm] = pl; er[gm] = pr; }
}

// ---- K3: bscatter (0..SC-1) + pair-scatter (SC..SC+PSC-1) + merged z GEMM.
__global__ __launch_bounds__(256) void zgemm_scatter_kernel(
    const float* __restrict__ Au, const __hip_bfloat16* __restrict__ Bpu,
    const float* __restrict__ bfu, const float* __restrict__ Ai,
    const __hip_bfloat16* __restrict__ Bpi, const float* __restrict__ bfi,
    const float* __restrict__ al, const float* __restrict__ ar, unsigned char* __restrict__ z8,
    float* __restrict__ el, float* __restrict__ er, int SC, int PSC, int GU,
    const int* __restrict__ src, const int* __restrict__ dst, int* __restrict__ gcur,
    unsigned int* __restrict__ scratch, int E,
    const int* __restrict__ ps, const int* __restrict__ pd, const int* __restrict__ ns,
    const int* __restrict__ nd, int* __restrict__ pgcur, uint2* __restrict__ pairbuf, int P) {
  __shared__ __align__(16) char smem[17408];
  int bx = blockIdx.x;
  if (bx < SC) {
    int* cnt = (int*)smem;
    int* basep = cnt + NB;
    for (int t = threadIdx.x; t < NB; t += 256) cnt[t] = 0;
    __syncthreads();
    const int i0 = bx * 4096;
    unsigned int v_[16];
    int b_[16], r_[16];
#pragma unroll
    for (int j = 0; j < 16; ++j) {
      int i = i0 + j * 256 + threadIdx.x;
      b_[j] = -1;
      if (i < E) {
        int d = dst[i];
        int s = src[i];
        int b = d >> BSH;
        b_[j] = b;
        r_[j] = atomicAdd(&cnt[b], 1);
        v_[j] = (unsigned int)s | ((unsigned int)(d & 511) << 17);
      }
    }
    __syncthreads();
    for (int t = threadIdx.x; t < NB; t += 256)
      basep[t] = cnt[t] ? atomicAdd(&gcur[t], cnt[t]) : 0;
    __syncthreads();
#pragma unroll
    for (int j = 0; j < 16; ++j)
      if (b_[j] >= 0) scratch[basep[b_[j]] + r_[j]] = v_[j];
    return;
  }
  if (bx < SC + PSC) {
    int* cnt = (int*)smem;
    int* basep = cnt + PB;
    for (int t = threadIdx.x; t < PB; t += 256) cnt[t] = 0;
    __syncthreads();
    const int TOT = 2 * P;
    const int i0 = (bx - SC) * 4096;
    unsigned int x_[16], y_[16];
    int b_[16], r_[16];
#pragma unroll
    for (int j = 0; j < 16; ++j) {
      int i = i0 + j * 256 + threadIdx.x;
      b_[j] = -1;
      if (i < TOT) {
        int a, b, wh;
        if (i < P) { a = ps[i]; b = pd[i]; wh = 0; }
        else { a = ns[i - P]; b = nd[i - P]; wh = 1; }
        int bk = a >> PBSH;
        b_[j] = bk;
        r_[j] = atomicAdd(&cnt[bk], 1);
        x_[j] = (unsigned int)a | ((unsigned int)wh << 17);
        y_[j] = (unsigned int)b;
      }
    }
    __syncthreads();
    for (int t = threadIdx.x; t < PB; t += 256)
      basep[t] = cnt[t] ? atomicAdd(&pgcur[t], cnt[t]) : 0;
    __syncthreads();
#pragma unroll
    for (int j = 0; j < 16; ++j)
      if (b_[j] >= 0) pairbuf[basep[b_[j]] + r_[j]] = make_uint2(x_[j], y_[j]);
    return;
  }
  int gb = bx - SC - PSC;
  if (gb < GU)
    zgemm_body<256>(smem, Au, Bpu, bfu, al, ar, z8, el, er, NUSER, gb);
  else
    zgemm_body<128>(smem, Ai, Bpi, bfi, al, ar, z8 + (size_t)NUSER * 128, el + NUSER, er + NUSER,
                    NITEM, gb - GU);
}

// ---- K4: per-bucket LDS counting sort -> ssrc (dst-sorted) + offs
__global__ __launch_bounds__(512) void bsort_kernel(const unsigned int* __restrict__ scratch,
                                                    const int* __restrict__ bstart,
                                                    int* __restrict__ offs, int* __restrict__ ssrc) {
  __shared__ unsigned int buf[CAP];
  __shared__ int cnt[512], scn[512], cur[512];
  int b = blockIdx.x, t = threadIdx.x;
  int s = bstart[b], e = bstart[b + 1], n = e - s;
  int d0 = b << BSH;
  int ndst = NNODE - d0;
  if (ndst > 512) ndst = 512;
  cnt[t] = 0;
  cur[t] = 0;
  __syncthreads();
  bool fit = (n <= CAP);
  if (fit) {
    for (int i = t; i < n; i += 512) {
      unsigned int v = scratch[s + i];
      buf[i] = v;
      atomicAdd(&cnt[v >> 17], 1);
    }
  } else {
    for (int i = t; i < n; i += 512) atomicAdd(&cnt[scratch[s + i] >> 17], 1);
  }
  __syncthreads();
  scn[t] = cnt[t];
  __syncthreads();
  for (int off = 1; off < 512; off <<= 1) {
    int a = (t >= off) ? scn[t - off] : 0;
    __syncthreads();
    scn[t] += a;
    __syncthreads();
  }
  int start = scn[t] - cnt[t];
  if (t < ndst) offs[d0 + t] = s + start;
  if (b == NB - 1 && t == 0) offs[NNODE] = e;
  __syncthreads();
  cnt[t] = start;
  __syncthreads();
  if (fit) {
    for (int i = t; i < n; i += 512) {
      unsigned int v = buf[i];
      int dl = v >> 17;
      int r = atomicAdd(&cur[dl], 1);
      ssrc[s + cnt[dl] + r] = (int)(v & 0x1FFFFu);
    }
  } else {
    for (int i = t; i < n; i += 512) {
      unsigned int v = scratch[s + i];
      int dl = v >> 17;
      int r = atomicAdd(&cur[dl], 1);
      ssrc[s + cnt[dl] + r] = (int)(v & 0x1FFFFu);
    }
  }
}

// ---- K5: GAT aggregation, paired-edge uint gathers.
// Lanes 0-31 gather edge i (4 fp8/lane), lanes 32-63 edge i+1; halves merged by shfl_xor(32).
__global__ __launch_bounds__(256) void aggregate_kernel(
    const unsigned char* __restrict__ z8, const float* __restrict__ el,
    const float* __restrict__ er, const int* __restrict__ offs, const int* __restrict__ ssrc,
    const float* __restrict__ gat_bias, __hip_bfloat16* __restrict__ h,
    unsigned char* __restrict__ h8) {
  __shared__ __align__(16) float2 ew[4][128];
  int wv = threadIdx.x >> 6, lane = threadIdx.x & 63;
  int half = lane >> 5, li = lane & 31;
  int d = blockIdx.x * 4 + wv;
  int s0 = offs[d], s1 = offs[d + 1];
  int deg = s1 - s0;
  float erd = er[d];
  const unsigned int* zwu = (const unsigned int*)z8;  // row = 32 uints (128 fp8)
  f32x2 acc01 = {0.f, 0.f}, acc23 = {0.f, 0.f};
  float ssum = 0.f;
  if (deg <= 128) {
    float w0 = 0.f, w1 = 0.f;
    int o0 = 0, o1 = 0;
    if (lane < deg) { int s = ssrc[s0 + lane]; o0 = s << 5; w0 = __expf(leaky02(el[s] + erd)); }
    if (64 + lane < deg) { int s = ssrc[s0 + 64 + lane]; o1 = s << 5; w1 = __expf(leaky02(el[s] + erd)); }
    ew[wv][lane] = make_float2(w0, __int_as_float(o0));
    ew[wv][64 + lane] = make_float2(w1, __int_as_float(o1));
    __builtin_amdgcn_wave_barrier();
    int i = 0;
    for (; i + 8 <= deg; i += 8) {
      float2 e0 = ew[wv][i + half];
      float2 e1 = ew[wv][i + 2 + half];
      float2 e2 = ew[wv][i + 4 + half];
      float2 e3 = ew[wv][i + 6 + half];
      unsigned int u0 = zwu[__float_as_uint(e0.y) + li];
      unsigned int u1 = zwu[__float_as_uint(e1.y) + li];
      unsigned int u2 = zwu[__float_as_uint(e2.y) + li];
      unsigned int u3 = zwu[__float_as_uint(e3.y) + li];
      ssum += (e0.x + e1.x) + (e2.x + e3.x);
      pairfma(acc01, acc23, e0.x, u0);
      pairfma(acc01, acc23, e1.x, u1);
      pairfma(acc01, acc23, e2.x, u2);
      pairfma(acc01, acc23, e3.x, u3);
    }
    for (; i + 2 <= deg; i += 2) {
      float2 e0 = ew[wv][i + half];
      unsigned int u0 = zwu[__float_as_uint(e0.y) + li];
      ssum += e0.x;
      pairfma(acc01, acc23, e0.x, u0);
    }
    // merge halves (cols match; lanes 0-31 become authoritative)
    acc01.x += __shfl_xor(acc01.x, 32, 64);
    acc01.y += __shfl_xor(acc01.y, 32, 64);
    acc23.x += __shfl_xor(acc23.x, 32, 64);
    acc23.y += __shfl_xor(acc23.y, 32, 64);
    ssum += __shfl_xor(ssum, 32, 64);
    if (i < deg && half == 0) {  // odd tail edge, lanes 0-31
      float2 e0 = ew[wv][i];
      unsigned int u0 = zwu[__float_as_uint(e0.y) + li];
      ssum += e0.x;
      pairfma(acc01, acc23, e0.x, u0);
    }
  } else {
    for (int i2 = s0; i2 < s1; ++i2) {
      int s = ssrc[i2];
      float w = __expf(leaky02(el[s] + erd));
      if (half == 0) {
        unsigned int u = zwu[((unsigned int)s << 5) + li];
        ssum += w;
        pairfma(acc01, acc23, w, u);
      }
    }
  }
  if (half == 0) {
    float inv = 1.f / ssum;
    float4 gb = *(const float4*)(gat_bias + li * 4);
    float o_[4];
    o_[0] = acc01.x * inv + gb.x;
    o_[1] = acc01.y * inv + gb.y;
    o_[2] = acc23.x * inv + gb.z;
    o_[3] = acc23.y * inv + gb.w;
#pragma unroll
    for (int j = 0; j < 4; ++j) o_[j] = (o_[j] > 0.f) ? o_[j] : (__expf(o_[j]) - 1.f);
    u16x4 hv;
    hv[0] = (unsigned short)f2bs(o_[0]);
    hv[1] = (unsigned short)f2bs(o_[1]);
    hv[2] = (unsigned short)f2bs(o_[2]);
    hv[3] = (unsigned short)f2bs(o_[3]);
    *(u16x4*)((unsigned short*)h + (size_t)d * 128 + li * 4) = hv;
    unsigned int pk = (unsigned int)__builtin_amdgcn_cvt_pk_fp8_f32(o_[0], o_[1], 0, false);
    pk = (unsigned int)__builtin_amdgcn_cvt_pk_fp8_f32(o_[2], o_[3], (int)pk, true);
    *(unsigned int*)(h8 + (size_t)d * 128 + li * 4) = pk;
  }
}

// ---- K6: predgemm (blocks 0..GP-1) + bucketed link scores (blocks GP..GP+PB-1).
__global__ __launch_bounds__(256) void scorepred_kernel(
    const unsigned char* __restrict__ h8, const uint2* __restrict__ pairbuf,
    const int* __restrict__ pbstart, float* __restrict__ l_all,
    unsigned int* __restrict__ maxacc,
    const __hip_bfloat16* __restrict__ h, const __hip_bfloat16* __restrict__ Bp,
    const float* __restrict__ bias, float* __restrict__ outp, int GP) {
  if ((int)blockIdx.x < GP) {
    const int lane = threadIdx.x & 63, wv = threadIdx.x >> 6;
    const int m0 = blockIdx.x * 64 + wv * 16;
    int arow = m0 + (lane & 15);
    if (arow >= NUSER) arow = NUSER - 1;
    const bf16x8* a0 = (const bf16x8*)(h + (size_t)arow * 128) + (lane >> 4);
    const bf16x8* bp = (const bf16x8*)Bp;
    f32x4 acc[4] = {};
#pragma unroll
    for (int ks = 0; ks < 4; ++ks) {
      bf16x8 af = a0[ks * 4];
#pragma unroll
      for (int nt = 0; nt < 4; ++nt) {
        bf16x8 bfr = bp[(ks * 4 + nt) * 64 + lane];
        acc[nt] = __builtin_amdgcn_mfma_f32_16x16x32_bf16(af, bfr, acc[nt], 0, 0, 0);
      }
    }
#pragma unroll
    for (int nt = 0; nt < 4; ++nt) {
      int col = nt * 16 + (lane & 15);
      float b = bias[col];
#pragma unroll
      for (int r = 0; r < 4; ++r) {
        int m = m0 + (lane >> 4) * 4 + r;
        if (m < NUSER) outp[(size_t)m * 64 + col] = acc[nt][r] + b;
      }
    }
    return;
  }
  const int sb = blockIdx.x - GP;
  const int g8 = threadIdx.x >> 3, l8 = threadIdx.x & 7;
  const uint4* h4 = (const uint4*)h8;
  const int sP = pbstart[sb], eP = pbstart[sb + 1];
  float mpos = -1e30f, mneg = -1e30f;

  int i = sP + g8;
  uint2 prC = make_uint2(0, 0);
  uint4 vaC = {0, 0, 0, 0}, vbC = {0, 0, 0, 0};
  if (i < eP) {
    prC = pairbuf[i];
    vaC = h4[(size_t)(prC.x & 0x1FFFFu) * 8 + l8];
    vbC = h4[(size_t)prC.y * 8 + l8];
  }
  int i1 = i + 32;
  uint2 prN = make_uint2(0, 0);
  if (i1 < eP) prN = pairbuf[i1];

  while (i < eP) {
    uint4 vaN = {0, 0, 0, 0}, vbN = {0, 0, 0, 0};
    if (i1 < eP) {
      vaN = h4[(size_t)(prN.x & 0x1FFFFu) * 8 + l8];
      vbN = h4[(size_t)prN.y * 8 + l8];
    }
    int i2 = i1 + 32;
    uint2 prN2 = make_uint2(0, 0);
    if (i2 < eP) prN2 = pairbuf[i2];
    f32x2 acc = {0.f, 0.f};
    fp8dot(acc, vaC.x, vbC.x);
    fp8dot(acc, vaC.y, vbC.y);
    fp8dot(acc, vaC.z, vbC.z);
    fp8dot(acc, vaC.w, vbC.w);
    float s = acc.x + acc.y;
    s += __shfl_xor(s, 1, 8);
    s += __shfl_xor(s, 2, 8);
    s += __shfl_xor(s, 4, 8);
    float lv = fminf(s, 0.f) - log1pf(__expf(-fabsf(s)));
    bool neg = (prC.x >> 17) & 1u;
    if (l8 == 0) l_all[i] = lv;
    if (neg) mneg = fmaxf(mneg, lv); else mpos = fmaxf(mpos, lv);
    i = i1; i1 = i2;
    prC = prN; prN = prN2;
    vaC = vaN; vbC = vbN;
  }
  __shared__ float red0[256], red1[256];
  red0[threadIdx.x] = mpos;
  red1[threadIdx.x] = mneg;
  __syncthreads();
  for (int off = 128; off; off >>= 1) {
    if (threadIdx.x < off) {
      red0[threadIdx.x] = fmaxf(red0[threadIdx.x], red0[threadIdx.x + off]);
      red1[threadIdx.x] = fmaxf(red1[threadIdx.x], red1[threadIdx.x + off]);
    }
    __syncthreads();
  }
  if (threadIdx.x == 0) {
    if (red0[0] > -1e29f) atomicMax(maxacc + 0, ord_of(red0[0]));
    if (red1[0] > -1e29f) atomicMax(maxacc + 1, ord_of(red1[0]));
  }
}

// ---- K7: thresholded sum over bucket-ordered l_all; last block writes loss.
__global__ __launch_bounds__(256) void loss_sum_kernel(const float* __restrict__ l_all,
                                                       const uint2* __restrict__ pairbuf,
                                                       const unsigned int* __restrict__ maxacc,
                                                       const int* __restrict__ alpha,
                                                       float* __restrict__ sums,
                                                       unsigned int* __restrict__ fincnt,
                                                       float* __restrict__ out, int TOT) {
  __shared__ float sd0[256], sd1[256];
  float a = (float)alpha[0];
  float kT = (0.5f <= a) ? 0.5f : a;
  float hold0 = kT * inv_ord(maxacc[0]);
  float hold1 = kT * inv_ord(maxacc[1]);
  float s0 = 0.f, s1 = 0.f;
  for (int i = blockIdx.x * 256 + threadIdx.x; i < TOT; i += gridDim.x * 256) {
    float v = l_all[i];
    if ((pairbuf[i].x >> 17) & 1u) {
      if (!(v > hold1)) s1 += v;
    } else {
      if (!(v > hold0)) s0 += v;
    }
  }
  sd0[threadIdx.x] = s0;
  sd1[threadIdx.x] = s1;
  __syncthreads();
  for (int off = 128; off; off >>= 1) {
    if (threadIdx.x < off) {
      sd0[threadIdx.x] += sd0[threadIdx.x + off];
      sd1[threadIdx.x] += sd1[threadIdx.x + off];
    }
    __syncthreads();
  }
  if (threadIdx.x == 0) {
    atomicAdd(&sums[0], sd0[0]);
    atomicAdd(&sums[1], sd1[0]);
    __threadfence();
    unsigned int t = atomicAdd(fincnt, 1u);
    if (t == gridDim.x - 1) {
      float f0 = atomicAdd(&sums[0], 0.f);
      float f1 = atomicAdd(&sums[1], 0.f);
      out[0] = -(f0 + f1);
    }
  }
}

extern "C" void kernel_launch(void* const* d_in, const int* in_sizes, int n_in,
                              void* d_out, int out_size, void* d_ws, size_t ws_size,
                              hipStream_t stream) {
  const float* feat_user = (const float*)d_in[0];
  const float* feat_item = (const float*)d_in[1];
  const float* W_user = (const float*)d_in[2];
  const float* b_user = (const float*)d_in[3];
  const float* W_item = (const float*)d_in[4];
  const float* b_item = (const float*)d_in[5];
  const float* W_gat = (const float*)d_in[6];
  const float* attn_l = (const float*)d_in[7];
  const float* attn_r = (const float*)d_in[8];
  const float* gat_bias = (const float*)d_in[9];
  const float* W_pred = (const float*)d_in[10];
  const float* b_pred = (const float*)d_in[11];
  const int* src = (const int*)d_in[12];
  const int* dst = (const int*)d_in[13];
  const int* pos_src = (const int*)d_in[14];
  const int* pos_dst = (const int*)d_in[15];
  const int* neg_src = (const int*)d_in[16];
  const int* neg_dst = (const int*)d_in[17];
  const int* alpha = (const int*)d_in[18];
  const int E = in_sizes[12];
  const int P = in_sizes[14];
  const int TOT = 2 * P;

  char* p = (char*)d_ws;
  auto alloc = [&](size_t bytes) {
    char* r = p;
    p += (bytes + 255) & ~(size_t)255;
    return r;
  };
  unsigned char* z8 = (unsigned char*)alloc((size_t)NNODE * 128);
  __hip_bfloat16* h = (__hip_bfloat16*)alloc((size_t)NNODE * 128 * 2);
  unsigned char* h8 = (unsigned char*)alloc((size_t)NNODE * 128);
  float* el = (float*)alloc((size_t)NNODE * 4);
  float* er = (float*)alloc((size_t)NNODE * 4);
  __hip_bfloat16* Bp_u = (__hip_bfloat16*)alloc(256 * 128 * 2);
  __hip_bfloat16* Bp_i = (__hip_bfloat16*)alloc(128 * 128 * 2);
  __hip_bfloat16* Bp_p = (__hip_bfloat16*)alloc(128 * 64 * 2);
  float* bf_u = (float*)alloc(128 * 4);
  float* bf_i = (float*)alloc(128 * 4);
  int* offs = (int*)alloc((size_t)(NNODE + 4) * 4);
  int* ssrc = (int*)alloc((size_t)E * 4);
  unsigned int* scratch = (unsigned int*)alloc((size_t)E * 4);
  uint2* pairbuf = (uint2*)alloc((size_t)TOT * 8);
  float* l_all = (float*)alloc((size_t)TOT * 4);
  int* bstart = (int*)alloc((NB + 1) * 4);
  int* gcur = (int*)alloc(NB * 4);
  int* pbstart = (int*)alloc((PB + 1) * 4);
  int* pgcur = (int*)alloc(PB * 4);
  // zero region: btotal[NB] | pbtotal[PB] | maxacc[2] | sums[2] | fincnt[1]
  int* btotal = (int*)alloc((NB + PB + 8) * 4);
  int* pbtotal = btotal + NB;
  unsigned int* maxacc = (unsigned int*)(pbtotal + PB);
  float* sums = (float*)(maxacc + 2);
  unsigned int* fincnt = (unsigned int*)(sums + 2);

  hipMemsetAsync(btotal, 0, (NB + PB + 8) * 4, stream);

  // K1: bucket counts + weight prep + pair counts (independent, fused)
  prep_count_kernel<<<512 + 225 + 128, 256, 0, stream>>>(
      W_user, b_user, W_item, b_item, W_gat, W_pred, Bp_u, Bp_i, Bp_p, bf_u, bf_i, dst, btotal, E,
      pos_src, neg_src, pbtotal, P);
  // K2: scan both bucket sets
  bscan_kernel<<<1, 256, 0, stream>>>(btotal, bstart, gcur, pbtotal, pbstart, pgcur);
  // K3: bscatter + pair-scatter (hidden under GEMM) + merged z GEMM
  const int GU = (NUSER + 63) / 64, GI = (NITEM + 63) / 64;
  const int SC = (E + 4095) / 4096;
  const int PSC = (TOT + 4095) / 4096;
  zgemm_scatter_kernel<<<SC + PSC + GU + GI, 256, 0, stream>>>(
      feat_user, Bp_u, bf_u, feat_item, Bp_i, bf_i, attn_l, attn_r, z8, el, er, SC, PSC, GU, src,
      dst, gcur, scratch, E, pos_src, pos_dst, neg_src, neg_dst, pgcur, pairbuf, P);
  // K4: per-bucket counting sort -> CSR
  bsort_kernel<<<NB, 512, 0, stream>>>(scratch, bstart, offs, ssrc);
  // K5: GAT edge-softmax aggregation (paired-edge gathers) -> h (bf16) + h8 (fp8)
  aggregate_kernel<<<NNODE / 4, 256, 0, stream>>>(z8, el, er, offs, ssrc, gat_bias, h, h8);
  // K6: predgemm + bucketed link scores
  const int GP = (NUSER + 63) / 64;
  scorepred_kernel<<<GP + PB, 256, 0, stream>>>(h8, pairbuf, pbstart, l_all, maxacc, h, Bp_p,
                                                b_pred, (float*)d_out + 1, GP);
  // K7: thresholded loss sums + final loss write (last block)
  loss_sum_kernel<<<1024, 256, 0, stream>>>(l_all, pairbuf, maxacc, alpha, sums, fincnt,
                                            (float*)d_out, TOT);

  (void)n_in; (void)out_size; (void)ws_size;
}

// Round 16
// 229.261 us; speedup vs baseline: 1.0657x; 1.0300x over previous
//
#include <hip/hip_runtime.h>
#include <hip/hip_bf16.h>
#include <math.h>

#define NUSER 60000
#define NITEM 60000
#define NNODE 120000
#define BSH 9
#define NB 235           // ceil(NNODE / 512) edge buckets
#define PBSH 7
#define PB 938           // ceil(NNODE / 128) pair buckets
#define CAP 8192         // per-bucket LDS capacity (edge sort)

typedef __attribute__((ext_vector_type(8))) short bf16x8;
typedef __attribute__((ext_vector_type(4))) float f32x4;
typedef __attribute__((ext_vector_type(2))) float f32x2;
typedef __attribute__((ext_vector_type(4))) unsigned short u16x4;

__device__ __forceinline__ float leaky02(float x) { return x > 0.f ? x : 0.2f * x; }

__device__ __forceinline__ float inv_ord(unsigned int u) {
  unsigned int bits = (u & 0x80000000u) ? (u & 0x7FFFFFFFu) : ~u;
  return __uint_as_float(bits);
}
__device__ __forceinline__ unsigned int ord_of(float f) {
  unsigned int u = __float_as_uint(f);
  return (u & 0x80000000u) ? ~u : (u | 0x80000000u);
}
__device__ __forceinline__ short f2bs(float f) {
  __hip_bfloat16 h = __float2bfloat16(f);
  return *reinterpret_cast<short*>(&h);
}

// acc01/acc23 += w * unpack4(u)  (4 fp8 -> cols 4li..4li+3)
__device__ __forceinline__ void pairfma(f32x2& a01, f32x2& a23, float w, unsigned int u) {
  f32x2 lo = __builtin_amdgcn_cvt_pk_f32_fp8(u, false);
  f32x2 hi = __builtin_amdgcn_cvt_pk_f32_fp8(u, true);
  f32x2 ww; ww.x = w; ww.y = w;
  a01 = __builtin_elementwise_fma(ww, lo, a01);
  a23 = __builtin_elementwise_fma(ww, hi, a23);
}
__device__ __forceinline__ void fp8dot(f32x2& acc, unsigned int ua, unsigned int ub) {
  f32x2 a0 = __builtin_amdgcn_cvt_pk_f32_fp8(ua, false);
  f32x2 a1 = __builtin_amdgcn_cvt_pk_f32_fp8(ua, true);
  f32x2 b0 = __builtin_amdgcn_cvt_pk_f32_fp8(ub, false);
  f32x2 b1 = __builtin_amdgcn_cvt_pk_f32_fp8(ub, true);
  acc = __builtin_elementwise_fma(a0, b0, acc);
  acc = __builtin_elementwise_fma(a1, b1, acc);
}

// ---- K1: bcount (0..511) + prep (512..736) + pair-count (737..864)
__global__ __launch_bounds__(256) void prep_count_kernel(
    const float* __restrict__ Wu, const float* __restrict__ bu, const float* __restrict__ Wi,
    const float* __restrict__ bi, const float* __restrict__ Wg, const float* __restrict__ Wp,
    __hip_bfloat16* __restrict__ Bp_u, __hip_bfloat16* __restrict__ Bp_i,
    __hip_bfloat16* __restrict__ Bp_p, float* __restrict__ bf_u, float* __restrict__ bf_i,
    const int* __restrict__ dst, int* __restrict__ btotal, int E,
    const int* __restrict__ ps, const int* __restrict__ ns, int* __restrict__ pbtotal, int P) {
  __shared__ int cnt[PB];
  if (blockIdx.x < 512) {
    int bid = blockIdx.x;
    for (int t = threadIdx.x; t < NB; t += 256) cnt[t] = 0;
    __syncthreads();
    for (int i = bid * 256 + threadIdx.x; i < E; i += 512 * 256)
      atomicAdd(&cnt[dst[i] >> BSH], 1);
    __syncthreads();
    for (int t = threadIdx.x; t < NB; t += 256)
      if (cnt[t]) atomicAdd(&btotal[t], cnt[t]);
    return;
  }
  if (blockIdx.x >= 737) {
    int bid = blockIdx.x - 737;
    int TOT = 2 * P;
    for (int t = threadIdx.x; t < PB; t += 256) cnt[t] = 0;
    __syncthreads();
    for (int i = bid * 256 + threadIdx.x; i < TOT; i += 128 * 256) {
      int a = (i < P) ? ps[i] : ns[i - P];
      atomicAdd(&cnt[a >> PBSH], 1);
    }
    __syncthreads();
    for (int t = threadIdx.x; t < PB; t += 256)
      if (cnt[t]) atomicAdd(&pbtotal[t], cnt[t]);
    return;
  }
  int t = (blockIdx.x - 512) * 256 + threadIdx.x;
  if (t < 32768) {
    int j = t & 7, lane = (t >> 3) & 63, rest = t >> 9;
    int nt = rest & 7, ks = rest >> 3;
    int k = ks * 32 + ((lane >> 4) << 3) + j;
    int n = nt * 16 + (lane & 15);
    float acc = 0.f;
#pragma unroll 8
    for (int jj = 0; jj < 128; ++jj) acc = fmaf(Wu[k * 128 + jj], Wg[jj * 128 + n], acc);
    Bp_u[t] = __float2bfloat16(acc);
  } else if (t < 49152) {
    int tt = t - 32768;
    int j = tt & 7, lane = (tt >> 3) & 63, rest = tt >> 9;
    int nt = rest & 7, ks = rest >> 3;
    int k = ks * 32 + ((lane >> 4) << 3) + j;
    int n = nt * 16 + (lane & 15);
    float acc = 0.f;
#pragma unroll 8
    for (int jj = 0; jj < 128; ++jj) acc = fmaf(Wi[k * 128 + jj], Wg[jj * 128 + n], acc);
    Bp_i[tt] = __float2bfloat16(acc);
  } else if (t < 57344) {
    int tt = t - 49152;
    int j = tt & 7, lane = (tt >> 3) & 63, rest = tt >> 9;
    int nt = rest & 3, ks = rest >> 2;
    int k = ks * 32 + ((lane >> 4) << 3) + j;
    int n = nt * 16 + (lane & 15);
    Bp_p[tt] = __float2bfloat16(Wp[k * 64 + n]);
  } else if (t < 57344 + 256) {
    int n = t - 57344;
    if (n < 128) {
      float acc = 0.f;
      for (int jj = 0; jj < 128; ++jj) acc = fmaf(bu[jj], Wg[jj * 128 + n], acc);
      bf_u[n] = acc;
    } else {
      int nn = n - 128;
      float acc = 0.f;
      for (int jj = 0; jj < 128; ++jj) acc = fmaf(bi[jj], Wg[jj * 128 + nn], acc);
      bf_i[nn] = acc;
    }
  }
}

// ---- K2: scan edge buckets (NB) and pair buckets (PB), one block.
__global__ void bscan_kernel(const int* __restrict__ btotal, int* __restrict__ bstart,
                             int* __restrict__ gcur, const int* __restrict__ pbtotal,
                             int* __restrict__ pbstart, int* __restrict__ pgcur) {
  __shared__ int s[256];
  int t = threadIdx.x;
  int v = (t < NB) ? btotal[t] : 0;
  s[t] = v;
  __syncthreads();
  for (int off = 1; off < 256; off <<= 1) {
    int a = (t >= off) ? s[t - off] : 0;
    __syncthreads();
    s[t] += a;
    __syncthreads();
  }
  int excl = s[t] - v;
  if (t < NB) { bstart[t] = excl; gcur[t] = excl; }
  if (t == NB - 1) bstart[NB] = s[t];
  __syncthreads();
  int v4[4], sum4 = 0;
#pragma unroll
  for (int k = 0; k < 4; ++k) {
    int idx = t * 4 + k;
    v4[k] = (idx < PB) ? pbtotal[idx] : 0;
    sum4 += v4[k];
  }
  s[t] = sum4;
  __syncthreads();
  for (int off = 1; off < 256; off <<= 1) {
    int a = (t >= off) ? s[t - off] : 0;
    __syncthreads();
    s[t] += a;
    __syncthreads();
  }
  int run = s[t] - sum4;
#pragma unroll
  for (int k = 0; k < 4; ++k) {
    int idx = t * 4 + k;
    if (idx < PB) { pbstart[idx] = run; pgcur[idx] = run; }
    run += v4[k];
  }
  if (t == 255) pbstart[PB] = s[255];
}

// ---- z GEMM body: B panel staged in LDS per K-half (fragment-linear 32KB memcpy),
// A-half hoisted in registers (8 float4 in flight) with next-half prefetch.
// Inner loop: ds_read_b128 B-fragments (~12cyc) instead of global (~200cyc).
template <int K>
__device__ __forceinline__ void zgemm_body(
    char* smem, const float* __restrict__ A, const __hip_bfloat16* __restrict__ Bp,
    const float* __restrict__ bias, const float* __restrict__ al, const float* __restrict__ ar,
    unsigned char* __restrict__ z8, float* __restrict__ el, float* __restrict__ er, int M,
    int blk) {
  const int lane = threadIdx.x & 63, wv = threadIdx.x >> 6;
  const int t = threadIdx.x;
  int arow = blk * 64 + wv * 16 + (lane & 15);
  if (arow >= M) arow = M - 1;
  const float* a0 = A + (size_t)arow * K + ((lane >> 4) << 3);
  const uint4* bsrc = (const uint4*)Bp;  // fragment-linear: frag f at uint4 offset f*64
  uint4* bl = (uint4*)smem;              // 32KB staging = 2048 uint4
  f32x4 acc[8] = {};
  constexpr int NH = K / 128;
  // hoist A half 0 (8 independent loads in flight)
  float4 a_[8];
#pragma unroll
  for (int f = 0; f < 8; ++f)
    a_[f] = *(const float4*)(a0 + (f >> 1) * 32 + (f & 1) * 4);
#pragma unroll
  for (int h = 0; h < NH; ++h) {
    // stage B half h: 32 fragments x 1KB contiguous; 8 uint4 per thread
#pragma unroll
    for (int r = 0; r < 8; ++r) bl[r * 256 + t] = bsrc[h * 2048 + r * 256 + t];
    __syncthreads();
    // prefetch A half h+1 while computing half h
    float4 an[8];
    if (h + 1 < NH) {
#pragma unroll
      for (int f = 0; f < 8; ++f)
        an[f] = *(const float4*)(a0 + (h + 1) * 128 + (f >> 1) * 32 + (f & 1) * 4);
    }
#pragma unroll
    for (int s = 0; s < 4; ++s) {
      float4 a1 = a_[s * 2], a2 = a_[s * 2 + 1];
      bf16x8 af;
      af[0] = f2bs(a1.x); af[1] = f2bs(a1.y); af[2] = f2bs(a1.z); af[3] = f2bs(a1.w);
      af[4] = f2bs(a2.x); af[5] = f2bs(a2.y); af[6] = f2bs(a2.z); af[7] = f2bs(a2.w);
#pragma unroll
      for (int nt = 0; nt < 8; ++nt) {
        bf16x8 bfr = *(const bf16x8*)&bl[(s * 8 + nt) * 64 + lane];
        acc[nt] = __builtin_amdgcn_mfma_f32_16x16x32_bf16(af, bfr, acc[nt], 0, 0, 0);
      }
    }
    __syncthreads();  // before overwriting B half (or entering epilogue)
    if (h + 1 < NH) {
#pragma unroll
      for (int f = 0; f < 8; ++f) a_[f] = an[f];
    }
  }
  // epilogue: two 64-col passes through 64x68 fp32 LDS; fused el/er + fp8 z
  float(*lds2)[68] = (float(*)[68])smem;
  int row = t >> 2, qq = t & 3;
  int gm = blk * 64 + row;
  float pl = 0.f, pr = 0.f;
#pragma unroll
  for (int p = 0; p < 2; ++p) {
    __syncthreads();
#pragma unroll
    for (int nt = p * 4; nt < p * 4 + 4; ++nt) {
      float b = bias[nt * 16 + (lane & 15)];
#pragma unroll
      for (int r = 0; r < 4; ++r)
        lds2[wv * 16 + (lane >> 4) * 4 + r][(nt & 3) * 16 + (lane & 15)] = acc[nt][r] + b;
    }
    __syncthreads();
    if (gm < M) {
#pragma unroll
      for (int v4 = 0; v4 < 2; ++v4) {
        float f[8];
#pragma unroll
        for (int j = 0; j < 8; ++j) {
          f[j] = lds2[row][qq * 16 + v4 * 8 + j];
          int c = p * 64 + qq * 16 + v4 * 8 + j;
          pl = fmaf(f[j], al[c], pl);
          pr = fmaf(f[j], ar[c], pr);
        }
        unsigned int w0 = (unsigned int)__builtin_amdgcn_cvt_pk_fp8_f32(f[0], f[1], 0, false);
        w0 = (unsigned int)__builtin_amdgcn_cvt_pk_fp8_f32(f[2], f[3], (int)w0, true);
        unsigned int w1 = (unsigned int)__builtin_amdgcn_cvt_pk_fp8_f32(f[4], f[5], 0, false);
        w1 = (unsigned int)__builtin_amdgcn_cvt_pk_fp8_f32(f[6], f[7], (int)w1, true);
        uint2 st; st.x = w0; st.y = w1;
        *(uint2*)(z8 + (size_t)gm * 128 + p * 64 + qq * 16 + v4 * 8) = st;
      }
    }
  }
  pl += __shfl_xor(pl, 1, 64); pl += __shfl_xor(pl, 2, 64);
  pr += __shfl_xor(pr, 1, 64); pr += __shfl_xor(pr, 2, 64);
  if (qq == 0 && gm < M) { el[gm] = pl; er[gm] = pr; }
}

// ---- K3: bscatter (0..SC-1) + pair-scatter (SC..SC+PSC-1) + merged z GEMM.
__global__ __launch_bounds__(256) void zgemm_scatter_kernel(
    const float* __restrict__ Au, const __hip_bfloat16* __restrict__ Bpu,
    const float* __restrict__ bfu, const float* __restrict__ Ai,
    const __hip_bfloat16* __restrict__ Bpi, const float* __restrict__ bfi,
    const float* __restrict__ al, const float* __restrict__ ar, unsigned char* __restrict__ z8,
    float* __restrict__ el, float* __restrict__ er, int SC, int PSC, int GU,
    const int* __restrict__ src, const int* __restrict__ dst, int* __restrict__ gcur,
    unsigned int* __restrict__ scratch, int E,
    const int* __restrict__ ps, const int* __restrict__ pd, const int* __restrict__ ns,
    const int* __restrict__ nd, int* __restrict__ pgcur, uint2* __restrict__ pairbuf, int P) {
  __shared__ __align__(16) char smem[32768];
  int bx = blockIdx.x;
  if (bx < SC) {
    int* cnt = (int*)smem;
    int* basep = cnt + NB;
    for (int t = threadIdx.x; t < NB; t += 256) cnt[t] = 0;
    __syncthreads();
    const int i0 = bx * 4096;
    unsigned int v_[16];
    int b_[16], r_[16];
#pragma unroll
    for (int j = 0; j < 16; ++j) {
      int i = i0 + j * 256 + threadIdx.x;
      b_[j] = -1;
      if (i < E) {
        int d = dst[i];
        int s = src[i];
        int b = d >> BSH;
        b_[j] = b;
        r_[j] = atomicAdd(&cnt[b], 1);
        v_[j] = (unsigned int)s | ((unsigned int)(d & 511) << 17);
      }
    }
    __syncthreads();
    for (int t = threadIdx.x; t < NB; t += 256)
      basep[t] = cnt[t] ? atomicAdd(&gcur[t], cnt[t]) : 0;
    __syncthreads();
#pragma unroll
    for (int j = 0; j < 16; ++j)
      if (b_[j] >= 0) scratch[basep[b_[j]] + r_[j]] = v_[j];
    return;
  }
  if (bx < SC + PSC) {
    int* cnt = (int*)smem;
    int* basep = cnt + PB;
    for (int t = threadIdx.x; t < PB; t += 256) cnt[t] = 0;
    __syncthreads();
    const int TOT = 2 * P;
    const int i0 = (bx - SC) * 4096;
    unsigned int x_[16], y_[16];
    int b_[16], r_[16];
#pragma unroll
    for (int j = 0; j < 16; ++j) {
      int i = i0 + j * 256 + threadIdx.x;
      b_[j] = -1;
      if (i < TOT) {
        int a, b, wh;
        if (i < P) { a = ps[i]; b = pd[i]; wh = 0; }
        else { a = ns[i - P]; b = nd[i - P]; wh = 1; }
        int bk = a >> PBSH;
        b_[j] = bk;
        r_[j] = atomicAdd(&cnt[bk], 1);
        x_[j] = (unsigned int)a | ((unsigned int)wh << 17);
        y_[j] = (unsigned int)b;
      }
    }
    __syncthreads();
    for (int t = threadIdx.x; t < PB; t += 256)
      basep[t] = cnt[t] ? atomicAdd(&pgcur[t], cnt[t]) : 0;
    __syncthreads();
#pragma unroll
    for (int j = 0; j < 16; ++j)
      if (b_[j] >= 0) pairbuf[basep[b_[j]] + r_[j]] = make_uint2(x_[j], y_[j]);
    return;
  }
  int gb = bx - SC - PSC;
  if (gb < GU)
    zgemm_body<256>(smem, Au, Bpu, bfu, al, ar, z8, el, er, NUSER, gb);
  else
    zgemm_body<128>(smem, Ai, Bpi, bfi, al, ar, z8 + (size_t)NUSER * 128, el + NUSER, er + NUSER,
                    NITEM, gb - GU);
}

// ---- K4: per-bucket LDS counting sort -> ssrc (dst-sorted) + offs
__global__ __launch_bounds__(512) void bsort_kernel(const unsigned int* __restrict__ scratch,
                                                    const int* __restrict__ bstart,
                                                    int* __restrict__ offs, int* __restrict__ ssrc) {
  __shared__ unsigned int buf[CAP];
  __shared__ int cnt[512], scn[512], cur[512];
  int b = blockIdx.x, t = threadIdx.x;
  int s = bstart[b], e = bstart[b + 1], n = e - s;
  int d0 = b << BSH;
  int ndst = NNODE - d0;
  if (ndst > 512) ndst = 512;
  cnt[t] = 0;
  cur[t] = 0;
  __syncthreads();
  bool fit = (n <= CAP);
  if (fit) {
    for (int i = t; i < n; i += 512) {
      unsigned int v = scratch[s + i];
      buf[i] = v;
      atomicAdd(&cnt[v >> 17], 1);
    }
  } else {
    for (int i = t; i < n; i += 512) atomicAdd(&cnt[scratch[s + i] >> 17], 1);
  }
  __syncthreads();
  scn[t] = cnt[t];
  __syncthreads();
  for (int off = 1; off < 512; off <<= 1) {
    int a = (t >= off) ? scn[t - off] : 0;
    __syncthreads();
    scn[t] += a;
    __syncthreads();
  }
  int start = scn[t] - cnt[t];
  if (t < ndst) offs[d0 + t] = s + start;
  if (b == NB - 1 && t == 0) offs[NNODE] = e;
  __syncthreads();
  cnt[t] = start;
  __syncthreads();
  if (fit) {
    for (int i = t; i < n; i += 512) {
      unsigned int v = buf[i];
      int dl = v >> 17;
      int r = atomicAdd(&cur[dl], 1);
      ssrc[s + cnt[dl] + r] = (int)(v & 0x1FFFFu);
    }
  } else {
    for (int i = t; i < n; i += 512) {
      unsigned int v = scratch[s + i];
      int dl = v >> 17;
      int r = atomicAdd(&cur[dl], 1);
      ssrc[s + cnt[dl] + r] = (int)(v & 0x1FFFFu);
    }
  }
}

// ---- K5: GAT aggregation, paired-edge uint gathers.
__global__ __launch_bounds__(256) void aggregate_kernel(
    const unsigned char* __restrict__ z8, const float* __restrict__ el,
    const float* __restrict__ er, const int* __restrict__ offs, const int* __restrict__ ssrc,
    const float* __restrict__ gat_bias, __hip_bfloat16* __restrict__ h,
    unsigned char* __restrict__ h8) {
  __shared__ __align__(16) float2 ew[4][128];
  int wv = threadIdx.x >> 6, lane = threadIdx.x & 63;
  int half = lane >> 5, li = lane & 31;
  int d = blockIdx.x * 4 + wv;
  int s0 = offs[d], s1 = offs[d + 1];
  int deg = s1 - s0;
  float erd = er[d];
  const unsigned int* zwu = (const unsigned int*)z8;
  f32x2 acc01 = {0.f, 0.f}, acc23 = {0.f, 0.f};
  float ssum = 0.f;
  if (deg <= 128) {
    float w0 = 0.f, w1 = 0.f;
    int o0 = 0, o1 = 0;
    if (lane < deg) { int s = ssrc[s0 + lane]; o0 = s << 5; w0 = __expf(leaky02(el[s] + erd)); }
    if (64 + lane < deg) { int s = ssrc[s0 + 64 + lane]; o1 = s << 5; w1 = __expf(leaky02(el[s] + erd)); }
    ew[wv][lane] = make_float2(w0, __int_as_float(o0));
    ew[wv][64 + lane] = make_float2(w1, __int_as_float(o1));
    __builtin_amdgcn_wave_barrier();
    int i = 0;
    for (; i + 8 <= deg; i += 8) {
      float2 e0 = ew[wv][i + half];
      float2 e1 = ew[wv][i + 2 + half];
      float2 e2 = ew[wv][i + 4 + half];
      float2 e3 = ew[wv][i + 6 + half];
      unsigned int u0 = zwu[__float_as_uint(e0.y) + li];
      unsigned int u1 = zwu[__float_as_uint(e1.y) + li];
      unsigned int u2 = zwu[__float_as_uint(e2.y) + li];
      unsigned int u3 = zwu[__float_as_uint(e3.y) + li];
      ssum += (e0.x + e1.x) + (e2.x + e3.x);
      pairfma(acc01, acc23, e0.x, u0);
      pairfma(acc01, acc23, e1.x, u1);
      pairfma(acc01, acc23, e2.x, u2);
      pairfma(acc01, acc23, e3.x, u3);
    }
    for (; i + 2 <= deg; i += 2) {
      float2 e0 = ew[wv][i + half];
      unsigned int u0 = zwu[__float_as_uint(e0.y) + li];
      ssum += e0.x;
      pairfma(acc01, acc23, e0.x, u0);
    }
    acc01.x += __shfl_xor(acc01.x, 32, 64);
    acc01.y += __shfl_xor(acc01.y, 32, 64);
    acc23.x += __shfl_xor(acc23.x, 32, 64);
    acc23.y += __shfl_xor(acc23.y, 32, 64);
    ssum += __shfl_xor(ssum, 32, 64);
    if (i < deg && half == 0) {
      float2 e0 = ew[wv][i];
      unsigned int u0 = zwu[__float_as_uint(e0.y) + li];
      ssum += e0.x;
      pairfma(acc01, acc23, e0.x, u0);
    }
  } else {
    for (int i2 = s0; i2 < s1; ++i2) {
      int s = ssrc[i2];
      float w = __expf(leaky02(el[s] + erd));
      if (half == 0) {
        unsigned int u = zwu[((unsigned int)s << 5) + li];
        ssum += w;
        pairfma(acc01, acc23, w, u);
      }
    }
  }
  if (half == 0) {
    float inv = 1.f / ssum;
    float4 gb = *(const float4*)(gat_bias + li * 4);
    float o_[4];
    o_[0] = acc01.x * inv + gb.x;
    o_[1] = acc01.y * inv + gb.y;
    o_[2] = acc23.x * inv + gb.z;
    o_[3] = acc23.y * inv + gb.w;
#pragma unroll
    for (int j = 0; j < 4; ++j) o_[j] = (o_[j] > 0.f) ? o_[j] : (__expf(o_[j]) - 1.f);
    u16x4 hv;
    hv[0] = (unsigned short)f2bs(o_[0]);
    hv[1] = (unsigned short)f2bs(o_[1]);
    hv[2] = (unsigned short)f2bs(o_[2]);
    hv[3] = (unsigned short)f2bs(o_[3]);
    *(u16x4*)((unsigned short*)h + (size_t)d * 128 + li * 4) = hv;
    unsigned int pk = (unsigned int)__builtin_amdgcn_cvt_pk_fp8_f32(o_[0], o_[1], 0, false);
    pk = (unsigned int)__builtin_amdgcn_cvt_pk_fp8_f32(o_[2], o_[3], (int)pk, true);
    *(unsigned int*)(h8 + (size_t)d * 128 + li * 4) = pk;
  }
}

// ---- K6: predgemm (blocks 0..GP-1) + bucketed link scores (blocks GP..GP+PB-1).
__global__ __launch_bounds__(256) void scorepred_kernel(
    const unsigned char* __restrict__ h8, const uint2* __restrict__ pairbuf,
    const int* __restrict__ pbstart, float* __restrict__ l_all,
    unsigned int* __restrict__ maxacc,
    const __hip_bfloat16* __restrict__ h, const __hip_bfloat16* __restrict__ Bp,
    const float* __restrict__ bias, float* __restrict__ outp, int GP) {
  if ((int)blockIdx.x < GP) {
    const int lane = threadIdx.x & 63, wv = threadIdx.x >> 6;
    const int m0 = blockIdx.x * 64 + wv * 16;
    int arow = m0 + (lane & 15);
    if (arow >= NUSER) arow = NUSER - 1;
    const bf16x8* a0 = (const bf16x8*)(h + (size_t)arow * 128) + (lane >> 4);
    const bf16x8* bp = (const bf16x8*)Bp;
    f32x4 acc[4] = {};
#pragma unroll
    for (int ks = 0; ks < 4; ++ks) {
      bf16x8 af = a0[ks * 4];
#pragma unroll
      for (int nt = 0; nt < 4; ++nt) {
        bf16x8 bfr = bp[(ks * 4 + nt) * 64 + lane];
        acc[nt] = __builtin_amdgcn_mfma_f32_16x16x32_bf16(af, bfr, acc[nt], 0, 0, 0);
      }
    }
#pragma unroll
    for (int nt = 0; nt < 4; ++nt) {
      int col = nt * 16 + (lane & 15);
      float b = bias[col];
#pragma unroll
      for (int r = 0; r < 4; ++r) {
        int m = m0 + (lane >> 4) * 4 + r;
        if (m < NUSER) outp[(size_t)m * 64 + col] = acc[nt][r] + b;
      }
    }
    return;
  }
  const int sb = blockIdx.x - GP;
  const int g8 = threadIdx.x >> 3, l8 = threadIdx.x & 7;
  const uint4* h4 = (const uint4*)h8;
  const int sP = pbstart[sb], eP = pbstart[sb + 1];
  float mpos = -1e30f, mneg = -1e30f;

  int i = sP + g8;
  uint2 prC = make_uint2(0, 0);
  uint4 vaC = {0, 0, 0, 0}, vbC = {0, 0, 0, 0};
  if (i < eP) {
    prC = pairbuf[i];
    vaC = h4[(size_t)(prC.x & 0x1FFFFu) * 8 + l8];
    vbC = h4[(size_t)prC.y * 8 + l8];
  }
  int i1 = i + 32;
  uint2 prN = make_uint2(0, 0);
  if (i1 < eP) prN = pairbuf[i1];

  while (i < eP) {
    uint4 vaN = {0, 0, 0, 0}, vbN = {0, 0, 0, 0};
    if (i1 < eP) {
      vaN = h4[(size_t)(prN.x & 0x1FFFFu) * 8 + l8];
      vbN = h4[(size_t)prN.y * 8 + l8];
    }
    int i2 = i1 + 32;
    uint2 prN2 = make_uint2(0, 0);
    if (i2 < eP) prN2 = pairbuf[i2];
    f32x2 acc = {0.f, 0.f};
    fp8dot(acc, vaC.x, vbC.x);
    fp8dot(acc, vaC.y, vbC.y);
    fp8dot(acc, vaC.z, vbC.z);
    fp8dot(acc, vaC.w, vbC.w);
    float s = acc.x + acc.y;
    s += __shfl_xor(s, 1, 8);
    s += __shfl_xor(s, 2, 8);
    s += __shfl_xor(s, 4, 8);
    float lv = fminf(s, 0.f) - log1pf(__expf(-fabsf(s)));
    bool neg = (prC.x >> 17) & 1u;
    if (l8 == 0) l_all[i] = lv;
    if (neg) mneg = fmaxf(mneg, lv); else mpos = fmaxf(mpos, lv);
    i = i1; i1 = i2;
    prC = prN; prN = prN2;
    vaC = vaN; vbC = vbN;
  }
  __shared__ float red0[256], red1[256];
  red0[threadIdx.x] = mpos;
  red1[threadIdx.x] = mneg;
  __syncthreads();
  for (int off = 128; off; off >>= 1) {
    if (threadIdx.x < off) {
      red0[threadIdx.x] = fmaxf(red0[threadIdx.x], red0[threadIdx.x + off]);
      red1[threadIdx.x] = fmaxf(red1[threadIdx.x], red1[threadIdx.x + off]);
    }
    __syncthreads();
  }
  if (threadIdx.x == 0) {
    if (red0[0] > -1e29f) atomicMax(maxacc + 0, ord_of(red0[0]));
    if (red1[0] > -1e29f) atomicMax(maxacc + 1, ord_of(red1[0]));
  }
}

// ---- K7: thresholded sum over bucket-ordered l_all; last block writes loss.
__global__ __launch_bounds__(256) void loss_sum_kernel(const float* __restrict__ l_all,
                                                       const uint2* __restrict__ pairbuf,
                                                       const unsigned int* __restrict__ maxacc,
                                                       const int* __restrict__ alpha,
                                                       float* __restrict__ sums,
                                                       unsigned int* __restrict__ fincnt,
                                                       float* __restrict__ out, int TOT) {
  __shared__ float sd0[256], sd1[256];
  float a = (float)alpha[0];
  float kT = (0.5f <= a) ? 0.5f : a;
  float hold0 = kT * inv_ord(maxacc[0]);
  float hold1 = kT * inv_ord(maxacc[1]);
  float s0 = 0.f, s1 = 0.f;
  for (int i = blockIdx.x * 256 + threadIdx.x; i < TOT; i += gridDim.x * 256) {
    float v = l_all[i];
    if ((pairbuf[i].x >> 17) & 1u) {
      if (!(v > hold1)) s1 += v;
    } else {
      if (!(v > hold0)) s0 += v;
    }
  }
  sd0[threadIdx.x] = s0;
  sd1[threadIdx.x] = s1;
  __syncthreads();
  for (int off = 128; off; off >>= 1) {
    if (threadIdx.x < off) {
      sd0[threadIdx.x] += sd0[threadIdx.x + off];
      sd1[threadIdx.x] += sd1[threadIdx.x + off];
    }
    __syncthreads();
  }
  if (threadIdx.x == 0) {
    atomicAdd(&sums[0], sd0[0]);
    atomicAdd(&sums[1], sd1[0]);
    __threadfence();
    unsigned int t = atomicAdd(fincnt, 1u);
    if (t == gridDim.x - 1) {
      float f0 = atomicAdd(&sums[0], 0.f);
      float f1 = atomicAdd(&sums[1], 0.f);
      out[0] = -(f0 + f1);
    }
  }
}

extern "C" void kernel_launch(void* const* d_in, const int* in_sizes, int n_in,
                              void* d_out, int out_size, void* d_ws, size_t ws_size,
                              hipStream_t stream) {
  const float* feat_user = (const float*)d_in[0];
  const float* feat_item = (const float*)d_in[1];
  const float* W_user = (const float*)d_in[2];
  const float* b_user = (const float*)d_in[3];
  const float* W_item = (const float*)d_in[4];
  const float* b_item = (const float*)d_in[5];
  const float* W_gat = (const float*)d_in[6];
  const float* attn_l = (const float*)d_in[7];
  const float* attn_r = (const float*)d_in[8];
  const float* gat_bias = (const float*)d_in[9];
  const float* W_pred = (const float*)d_in[10];
  const float* b_pred = (const float*)d_in[11];
  const int* src = (const int*)d_in[12];
  const int* dst = (const int*)d_in[13];
  const int* pos_src = (const int*)d_in[14];
  const int* pos_dst = (const int*)d_in[15];
  const int* neg_src = (const int*)d_in[16];
  const int* neg_dst = (const int*)d_in[17];
  const int* alpha = (const int*)d_in[18];
  const int E = in_sizes[12];
  const int P = in_sizes[14];
  const int TOT = 2 * P;

  char* p = (char*)d_ws;
  auto alloc = [&](size_t bytes) {
    char* r = p;
    p += (bytes + 255) & ~(size_t)255;
    return r;
  };
  unsigned char* z8 = (unsigned char*)alloc((size_t)NNODE * 128);
  __hip_bfloat16* h = (__hip_bfloat16*)alloc((size_t)NNODE * 128 * 2);
  unsigned char* h8 = (unsigned char*)alloc((size_t)NNODE * 128);
  float* el = (float*)alloc((size_t)NNODE * 4);
  float* er = (float*)alloc((size_t)NNODE * 4);
  __hip_bfloat16* Bp_u = (__hip_bfloat16*)alloc(256 * 128 * 2);
  __hip_bfloat16* Bp_i = (__hip_bfloat16*)alloc(128 * 128 * 2);
  __hip_bfloat16* Bp_p = (__hip_bfloat16*)alloc(128 * 64 * 2);
  float* bf_u = (float*)alloc(128 * 4);
  float* bf_i = (float*)alloc(128 * 4);
  int* offs = (int*)alloc((size_t)(NNODE + 4) * 4);
  int* ssrc = (int*)alloc((size_t)E * 4);
  unsigned int* scratch = (unsigned int*)alloc((size_t)E * 4);
  uint2* pairbuf = (uint2*)alloc((size_t)TOT * 8);
  float* l_all = (float*)alloc((size_t)TOT * 4);
  int* bstart = (int*)alloc((NB + 1) * 4);
  int* gcur = (int*)alloc(NB * 4);
  int* pbstart = (int*)alloc((PB + 1) * 4);
  int* pgcur = (int*)alloc(PB * 4);
  // zero region: btotal[NB] | pbtotal[PB] | maxacc[2] | sums[2] | fincnt[1]
  int* btotal = (int*)alloc((NB + PB + 8) * 4);
  int* pbtotal = btotal + NB;
  unsigned int* maxacc = (unsigned int*)(pbtotal + PB);
  float* sums = (float*)(maxacc + 2);
  unsigned int* fincnt = (unsigned int*)(sums + 2);

  hipMemsetAsync(btotal, 0, (NB + PB + 8) * 4, stream);

  // K1: bucket counts + weight prep + pair counts (independent, fused)
  prep_count_kernel<<<512 + 225 + 128, 256, 0, stream>>>(
      W_user, b_user, W_item, b_item, W_gat, W_pred, Bp_u, Bp_i, Bp_p, bf_u, bf_i, dst, btotal, E,
      pos_src, neg_src, pbtotal, P);
  // K2: scan both bucket sets
  bscan_kernel<<<1, 256, 0, stream>>>(btotal, bstart, gcur, pbtotal, pbstart, pgcur);
  // K3: bscatter + pair-scatter (hidden under GEMM) + z GEMM with B-in-LDS
  const int GU = (NUSER + 63) / 64, GI = (NITEM + 63) / 64;
  const int SC = (E + 4095) / 4096;
  const int PSC = (TOT + 4095) / 4096;
  zgemm_scatter_kernel<<<SC + PSC + GU + GI, 256, 0, stream>>>(
      feat_user, Bp_u, bf_u, feat_item, Bp_i, bf_i, attn_l, attn_r, z8, el, er, SC, PSC, GU, src,
      dst, gcur, scratch, E, pos_src, pos_dst, neg_src, neg_dst, pgcur, pairbuf, P);
  // K4: per-bucket counting sort -> CSR
  bsort_kernel<<<NB, 512, 0, stream>>>(scratch, bstart, offs, ssrc);
  // K5: GAT edge-softmax aggregation (paired-edge gathers) -> h (bf16) + h8 (fp8)
  aggregate_kernel<<<NNODE / 4, 256, 0, stream>>>(z8, el, er, offs, ssrc, gat_bias, h, h8);
  // K6: predgemm + bucketed link scores
  const int GP = (NUSER + 63) / 64;
  scorepred_kernel<<<GP + PB, 256, 0, stream>>>(h8, pairbuf, pbstart, l_all, maxacc, h, Bp_p,
                                                b_pred, (float*)d_out + 1, GP);
  // K7: thresholded loss sums + final loss write (last block)
  loss_sum_kernel<<<1024, 256, 0, stream>>>(l_all, pairbuf, maxacc, alpha, sums, fincnt,
                                            (float*)d_out, TOT);

  (void)n_in; (void)out_size; (void)ws_size;
}